// Round 1
// baseline (18277.962 us; speedup 1.0000x reference)
//
#include <hip/hip_runtime.h>
#include <math.h>

#define Bn 32
#define Tn 64
#define An 6
#define Ln 32
#define Hn 128
#define FDn 256
#define Nimg (Bn*Tn)   // 2048

__device__ __forceinline__ float sigmoidf(float x){ return 1.f/(1.f + expf(-x)); }

// ---------------------------------------------------------------------------
// Direct conv: k=4, stride=2, pad=1. One thread computes KPT output channels
// at one output pixel. Weight loads are (near-)warp-uniform -> L1 broadcast.
// ---------------------------------------------------------------------------
template<int C, int IN, int K, int OUT, int KPT>
__global__ void __launch_bounds__(256)
conv4s2_kernel(const float* __restrict__ in, const float* __restrict__ w,
               const float* __restrict__ bias, float* __restrict__ out, int N)
{
  const int KG = K / KPT;
  const int total = N * KG * OUT * OUT;
  for (int idx = blockIdx.x * blockDim.x + threadIdx.x; idx < total;
       idx += gridDim.x * blockDim.x) {
    const int sp  = idx & (OUT*OUT - 1);
    const int tmp = idx / (OUT*OUT);
    const int kg  = tmp & (KG - 1);
    const int n   = tmp / KG;
    const int oy  = sp / OUT, ox = sp & (OUT - 1);

    float acc[KPT];
#pragma unroll
    for (int j = 0; j < KPT; j++) acc[j] = bias[kg*KPT + j];

    const float* inN = in + (size_t)n * C * IN * IN;
    const float* wK  = w  + (size_t)(kg*KPT) * C * 16;
#pragma unroll 1
    for (int c = 0; c < C; c++){
      const float* inC = inN + c * IN * IN;
      const float* wC  = wK  + c * 16;
#pragma unroll
      for (int kh = 0; kh < 4; kh++){
        const int iy = oy*2 - 1 + kh;
        if (iy < 0 || iy >= IN) continue;
#pragma unroll
        for (int kw = 0; kw < 4; kw++){
          const int ix = ox*2 - 1 + kw;
          if (ix < 0 || ix >= IN) continue;
          const float v = inC[iy*IN + ix];
#pragma unroll
          for (int j = 0; j < KPT; j++)
            acc[j] = fmaf(v, wC[(size_t)j*C*16 + kh*4 + kw], acc[j]);
        }
      }
    }
    float* outN = out + ((size_t)n*K + kg*KPT) * OUT * OUT + sp;
#pragma unroll
    for (int j = 0; j < KPT; j++) outN[(size_t)j*OUT*OUT] = fmaxf(acc[j], 0.f);
  }
}

// ---------------------------------------------------------------------------
// FC: out[n][o] = in[n][:] . w[o][:] + b[o], via transposed weights wT[k][o]
// (coalesced over o). NB batch rows per thread; in-row loads are
// block-uniform -> scalar loads.
// ---------------------------------------------------------------------------
template<int NB>
__global__ void __launch_bounds__(256)
fc_kernel(const float* __restrict__ in, const float* __restrict__ wT,
          const float* __restrict__ bias, float* __restrict__ out,
          int Kd, int O)
{
  const int o  = threadIdx.x;          // O == 256 threads
  const int n0 = blockIdx.x * NB;
  float acc[NB];
  const float bv = bias[o];
#pragma unroll
  for (int j = 0; j < NB; j++) acc[j] = bv;
  for (int k = 0; k < Kd; k++){
    const float wv = wT[(size_t)k*O + o];
#pragma unroll
    for (int j = 0; j < NB; j++)
      acc[j] = fmaf(wv, in[(size_t)(n0+j)*Kd + k], acc[j]);
  }
#pragma unroll
  for (int j = 0; j < NB; j++) out[(size_t)(n0+j)*O + o] = acc[j];
}

// ---------------------------------------------------------------------------
__global__ void transpose_kernel(const float* __restrict__ src,
                                 float* __restrict__ dst, int rows, int cols)
{
  int i = blockIdx.x * blockDim.x + threadIdx.x;
  if (i < rows * cols){
    int r = i / cols, c = i - r*cols;
    dst[(size_t)c*rows + r] = src[i];
  }
}

// ---------------------------------------------------------------------------
// RSSM scan: one block per batch element, 384 threads (one per GRU gate out).
// h, z, gates in LDS; T=64 sequential steps.
// ---------------------------------------------------------------------------
__global__ void __launch_bounds__(384)
rssm_scan(const float* __restrict__ actions, const float* __restrict__ feats,
          const float* __restrict__ eps,
          const float* __restrict__ wihT,  // (38,384)
          const float* __restrict__ whhT,  // (128,384)
          const float* __restrict__ bih,  const float* __restrict__ bhh,
          const float* __restrict__ priorT, // (128,64)
          const float* __restrict__ prior_b,
          const float* __restrict__ postT,  // (384,64)
          const float* __restrict__ post_b,
          float* __restrict__ out)
{
  const int b   = blockIdx.x;
  const int tid = threadIdx.x;

  __shared__ float sh_h[Hn];
  __shared__ float sh_x[Ln + An];
  __shared__ float sh_f[FDn];
  __shared__ float sh_gi[3*Hn];
  __shared__ float sh_gh[3*Hn];
  __shared__ float sh_pq[64];
  __shared__ float sh_z[Ln];

  if (tid < Hn) sh_h[tid] = 0.f;
  if (tid >= Hn && tid < Hn + Ln) sh_z[tid - Hn] = 0.f;
  __syncthreads();

  const int OFF_MUP = 0;
  const int OFF_LVP = Bn*Tn*Ln;
  const int OFF_MUQ = 2*Bn*Tn*Ln;
  const int OFF_LVQ = 3*Bn*Tn*Ln;
  const int OFF_H   = 4*Bn*Tn*Ln;
  const int OFF_Z   = 4*Bn*Tn*Ln + Bn*Tn*Hn;

  for (int t = 0; t < Tn; t++){
    const int bt = b*Tn + t;
    // build x = [z, a_t]; stage f_t
    if (tid < Ln) sh_x[tid] = sh_z[tid];
    else if (tid < Ln + An) sh_x[tid] = actions[(size_t)bt*An + (tid - Ln)];
    else if (tid >= 64 && tid < 64 + FDn) sh_f[tid - 64] = feats[(size_t)bt*FDn + (tid - 64)];
    __syncthreads();

    // gi[i] = x . wih[i] + bih[i];  gh[i] = h . whh[i] + bhh[i]
    {
      const int i = tid;
      float gi0 = bih[i], gi1 = 0.f;
#pragma unroll
      for (int k = 0; k < Ln + An; k += 2){
        gi0 = fmaf(wihT[(k+0)*384 + i], sh_x[k+0], gi0);
        gi1 = fmaf(wihT[(k+1)*384 + i], sh_x[k+1], gi1);
      }
      float g0 = bhh[i], g1 = 0.f, g2 = 0.f, g3 = 0.f;
      for (int k = 0; k < Hn; k += 4){
        g0 = fmaf(whhT[(k+0)*384 + i], sh_h[k+0], g0);
        g1 = fmaf(whhT[(k+1)*384 + i], sh_h[k+1], g1);
        g2 = fmaf(whhT[(k+2)*384 + i], sh_h[k+2], g2);
        g3 = fmaf(whhT[(k+3)*384 + i], sh_h[k+3], g3);
      }
      sh_gi[i] = gi0 + gi1;
      sh_gh[i] = (g0 + g1) + (g2 + g3);
    }
    __syncthreads();

    float hnew = 0.f;
    if (tid < Hn){
      const float r  = sigmoidf(sh_gi[tid]      + sh_gh[tid]);
      const float zg = sigmoidf(sh_gi[Hn + tid] + sh_gh[Hn + tid]);
      const float nn = tanhf(fmaf(r, sh_gh[2*Hn + tid], sh_gi[2*Hn + tid]));
      hnew = (1.f - zg)*nn + zg*sh_h[tid];
    }
    __syncthreads();           // everyone done reading old sh_h
    if (tid < Hn){
      sh_h[tid] = hnew;
      out[OFF_H + (size_t)bt*Hn + tid] = hnew;
    }
    __syncthreads();

    // prior (threads 0..63) and posterior (threads 64..127)
    if (tid < 64){
      const int o = tid;
      float a0 = prior_b[o], a1 = 0.f, a2 = 0.f, a3 = 0.f;
      for (int k = 0; k < Hn; k += 4){
        a0 = fmaf(priorT[(k+0)*64 + o], sh_h[k+0], a0);
        a1 = fmaf(priorT[(k+1)*64 + o], sh_h[k+1], a1);
        a2 = fmaf(priorT[(k+2)*64 + o], sh_h[k+2], a2);
        a3 = fmaf(priorT[(k+3)*64 + o], sh_h[k+3], a3);
      }
      const float p = (a0 + a1) + (a2 + a3);
      if (o < Ln) out[OFF_MUP + (size_t)bt*Ln + o] = p;
      else        out[OFF_LVP + (size_t)bt*Ln + (o - Ln)] = p;
    } else if (tid < 128){
      const int o = tid - 64;
      float a0 = post_b[o], a1 = 0.f, a2 = 0.f, a3 = 0.f;
      for (int k = 0; k < Hn; k += 4){
        a0 = fmaf(postT[(k+0)*64 + o], sh_h[k+0], a0);
        a1 = fmaf(postT[(k+1)*64 + o], sh_h[k+1], a1);
        a2 = fmaf(postT[(k+2)*64 + o], sh_h[k+2], a2);
        a3 = fmaf(postT[(k+3)*64 + o], sh_h[k+3], a3);
      }
      for (int k = 0; k < FDn; k += 4){
        a0 = fmaf(postT[(Hn+k+0)*64 + o], sh_f[k+0], a0);
        a1 = fmaf(postT[(Hn+k+1)*64 + o], sh_f[k+1], a1);
        a2 = fmaf(postT[(Hn+k+2)*64 + o], sh_f[k+2], a2);
        a3 = fmaf(postT[(Hn+k+3)*64 + o], sh_f[k+3], a3);
      }
      const float q = (a0 + a1) + (a2 + a3);
      sh_pq[o] = q;
      if (o < Ln) out[OFF_MUQ + (size_t)bt*Ln + o] = q;
      else        out[OFF_LVQ + (size_t)bt*Ln + (o - Ln)] = q;
    }
    __syncthreads();

    if (tid < Ln){
      const float mu = sh_pq[tid], lv = sh_pq[Ln + tid];
      const float zz = fmaf(expf(0.5f*lv), eps[(size_t)bt*Ln + tid], mu);
      sh_z[tid] = zz;
      out[OFF_Z + (size_t)bt*Ln + tid] = zz;
    }
    __syncthreads();
  }
}

// ---------------------------------------------------------------------------
extern "C" void kernel_launch(void* const* d_in, const int* in_sizes, int n_in,
                              void* d_out, int out_size, void* d_ws, size_t ws_size,
                              hipStream_t stream)
{
  const float* states = (const float*)d_in[0];
  const float* actions= (const float*)d_in[1];
  const float* c1_w = (const float*)d_in[2];  const float* c1_b = (const float*)d_in[3];
  const float* c2_w = (const float*)d_in[4];  const float* c2_b = (const float*)d_in[5];
  const float* c3_w = (const float*)d_in[6];  const float* c3_b = (const float*)d_in[7];
  const float* c4_w = (const float*)d_in[8];  const float* c4_b = (const float*)d_in[9];
  const float* fc_w = (const float*)d_in[10]; const float* fc_b = (const float*)d_in[11];
  const float* gwih = (const float*)d_in[12]; const float* gwhh = (const float*)d_in[13];
  const float* gbih = (const float*)d_in[14]; const float* gbhh = (const float*)d_in[15];
  const float* pr_w = (const float*)d_in[16]; const float* pr_b = (const float*)d_in[17];
  const float* po_w = (const float*)d_in[18]; const float* po_b = (const float*)d_in[19];
  const float* eps  = (const float*)d_in[20];

  float* ws     = (float*)d_ws;
  float* bufC   = ws;                               // 2048*4096 (conv4 out, full N)
  float* feats  = bufC   + (size_t)Nimg*4096;       // 2048*256
  float* fc_wT  = feats  + (size_t)Nimg*FDn;        // 4096*256
  float* wihT   = fc_wT  + (size_t)4096*256;        // 38*384
  float* whhT   = wihT   + 38*384;                  // 128*384
  float* priorT = whhT   + 128*384;                 // 128*64
  float* postT  = priorT + 128*64;                  // 384*64
  float* bufA   = postT  + 384*64;
  const size_t fixed = (size_t)(bufA - ws);

  // pick largest chunk of images whose ping-pong buffers fit the workspace
  int NC = Nimg;
  while (NC > 64 && (fixed + (size_t)NC*49152) * sizeof(float) > ws_size) NC >>= 1;
  float* bufB = bufA + (size_t)NC*32768;

  // weight transposes (idempotent, every call)
  transpose_kernel<<<(256*4096+255)/256, 256, 0, stream>>>(fc_w, fc_wT, 256, 4096);
  transpose_kernel<<<(384*38  +255)/256, 256, 0, stream>>>(gwih, wihT, 384, 38);
  transpose_kernel<<<(384*128 +255)/256, 256, 0, stream>>>(gwhh, whhT, 384, 128);
  transpose_kernel<<<(64*128  +255)/256, 256, 0, stream>>>(pr_w, priorT, 64, 128);
  transpose_kernel<<<(64*384  +255)/256, 256, 0, stream>>>(po_w, postT, 64, 384);

  for (int c0 = 0; c0 < Nimg; c0 += NC){
    conv4s2_kernel<3,64,32,32,4>
      <<< NC*8*1024/256, 256, 0, stream >>>(states + (size_t)c0*3*64*64, c1_w, c1_b, bufA, NC);
    conv4s2_kernel<32,32,64,16,4>
      <<< NC*16*256/256, 256, 0, stream >>>(bufA, c2_w, c2_b, bufB, NC);
    conv4s2_kernel<64,16,128,8,4>
      <<< NC*32*64/256, 256, 0, stream >>>(bufB, c3_w, c3_b, bufA, NC);
    conv4s2_kernel<128,8,256,4,4>
      <<< NC*64*16/256, 256, 0, stream >>>(bufA, c4_w, c4_b, bufC + (size_t)c0*4096, NC);
  }

  fc_kernel<8><<< Nimg/8, 256, 0, stream >>>(bufC, fc_wT, fc_b, feats, 4096, 256);

  rssm_scan<<< Bn, 384, 0, stream >>>(actions, feats, eps, wihT, whhT, gbih, gbhh,
                                      priorT, pr_b, postT, po_b, (float*)d_out);
}

// Round 2
// 2595.130 us; speedup vs baseline: 7.0432x; 7.0432x over previous
//
#include <hip/hip_runtime.h>
#include <math.h>

#define Bn 32
#define Tn 64
#define An 6
#define Ln 32
#define Hn 128
#define FDn 256
#define Nimg (Bn*Tn)   // 2048

typedef __attribute__((ext_vector_type(8))) short frag_ab;   // 8 bf16
typedef __attribute__((ext_vector_type(4))) float frag_cd;   // 4 fp32

__device__ __forceinline__ float sigmoidf(float x){ return 1.f/(1.f + expf(-x)); }

__device__ __forceinline__ unsigned short f2bf(float f){
  unsigned int u = __float_as_uint(f);
  unsigned int r = (u + 0x7fffu + ((u >> 16) & 1u)) >> 16;
  return (unsigned short)r;
}

// ---------------------------------------------------------------------------
// fp32 -> bf16 conversion, 4 elems/thread (n divisible by 4)
// ---------------------------------------------------------------------------
__global__ void __launch_bounds__(256)
f2bf_kernel(const float* __restrict__ src, unsigned short* __restrict__ dst, int n)
{
  int i = (blockIdx.x * blockDim.x + threadIdx.x) * 4;
  if (i < n){
    float4 f = *(const float4*)(src + i);
    union { unsigned short s[4]; uint2 v; } u;
    u.s[0]=f2bf(f.x); u.s[1]=f2bf(f.y); u.s[2]=f2bf(f.z); u.s[3]=f2bf(f.w);
    *(uint2*)(dst + i) = u.v;
  }
}

// conv1 weights: (32,3,4,4) fp32 -> (32,4,16) bf16 with channel 3 zero-padded
__global__ void __launch_bounds__(256)
conv1w_kernel(const float* __restrict__ src, unsigned short* __restrict__ dst)
{
  int i = blockIdx.x * blockDim.x + threadIdx.x;   // 32*64
  if (i < 32*64){
    int k = i >> 6, r = i & 63;
    int c = r >> 4, tap = r & 15;
    dst[i] = (c < 3) ? f2bf(src[(k*3 + c)*16 + tap]) : (unsigned short)0;
  }
}

__global__ void transpose_kernel(const float* __restrict__ src,
                                 float* __restrict__ dst, int rows, int cols)
{
  int i = blockIdx.x * blockDim.x + threadIdx.x;
  if (i < rows * cols){
    int r = i / cols, c = i - r*cols;
    dst[(size_t)c*rows + r] = src[i];
  }
}

// ---------------------------------------------------------------------------
// Implicit-GEMM conv (k=4, s=2, p=1) on MFMA 16x16x32 bf16.
//   M = Nimg*OUT*OUT (output pixels), N = Kout, K = Cin*16.
//   A row m = im2col(input);  B^T row n = w[n][.] (weights already B^T).
// Block: 256 thr = 4 waves. Tile BM=64 x BN. K-step 32 (= 2 channels).
// LDS rows padded to 40 bf16 (80 B) -> conflict-free ds_read_b128.
// ---------------------------------------------------------------------------
template<int Cin, int CinReal, int IN, int Kout, int OUT, int BN>
__global__ void __launch_bounds__(256)
conv_mfma(const unsigned short* __restrict__ in, const unsigned short* __restrict__ wB,
          const float* __restrict__ bias, unsigned short* __restrict__ out)
{
  constexpr int SPB = OUT*OUT;
  constexpr int KD  = Cin*16;
  __shared__ __align__(16) unsigned short Alds[64*40];
  __shared__ __align__(16) unsigned short Blds[BN*40];

  const int tid  = threadIdx.x;
  const int wave = tid >> 6, lane = tid & 63;
  const unsigned m0 = blockIdx.x * 64;
  const int n0 = blockIdx.y * BN;

  // ---- A-gather geometry (loop-invariant) ----
  const int ar  = tid >> 2;          // row in tile 0..63
  const int aq  = tid & 3;           // quad
  const int c2  = aq >> 1;           // channel within K-step
  const int kh0 = (aq & 1) * 2;      // kh pair base
  const unsigned m   = m0 + ar;
  const unsigned nim = m / SPB;
  const unsigned sp  = m % SPB;
  const int oy = sp / OUT, ox = sp % OUT;
  const int ix0 = ox*2 - 1;
  const unsigned short* inN = in + (size_t)nim * CinReal * IN * IN;
  int  iyoff[2]; bool iyok[2];
#pragma unroll
  for (int dh = 0; dh < 2; dh++){
    int iy = oy*2 - 1 + kh0 + dh;
    iyok[dh]  = (iy >= 0 && iy < IN);
    iyoff[dh] = iyok[dh] ? iy*IN : 0;
  }
  bool ixok[4];
#pragma unroll
  for (int kw = 0; kw < 4; kw++) ixok[kw] = (ix0+kw >= 0 && ix0+kw < IN);
  unsigned short* Adst = &Alds[ar*40 + c2*16 + kh0*4];

  // ---- B-stage geometry ----
  const int bn = tid >> 2;           // 0..63 (only < BN used)
  const int bi = tid & 3;
  const unsigned short* Bsrc = wB + (size_t)(n0 + bn)*KD + bi*8;
  unsigned short* Bdst = &Blds[bn*40 + bi*8];

  frag_cd acc[BN/16];
#pragma unroll
  for (int g = 0; g < BN/16; g++) acc[g] = (frag_cd){0.f,0.f,0.f,0.f};

  const int lrow = lane & 15;
  const int lk   = (lane >> 4) * 8;

#pragma unroll 1
  for (int kt = 0; kt < KD/32; kt++){
    // stage A (im2col gather, 8 bf16/thread)
    {
      union { unsigned short s[8]; uint4 v; } va;
#pragma unroll
      for (int j = 0; j < 8; j++) va.s[j] = 0;
      const int c = kt*2 + c2;
      if (Cin == CinReal || c < CinReal){
        const unsigned short* ip = inN + (size_t)c * IN * IN;
#pragma unroll
        for (int dh = 0; dh < 2; dh++){
          if (iyok[dh]){
#pragma unroll
            for (int kw = 0; kw < 4; kw++)
              if (ixok[kw]) va.s[dh*4+kw] = ip[iyoff[dh] + ix0 + kw];
          }
        }
      }
      *(uint4*)Adst = va.v;
    }
    // stage B (coalesced 16B rows of w)
    if (tid < BN*4)
      *(uint4*)Bdst = *(const uint4*)(Bsrc + kt*32);
    __syncthreads();

    frag_ab a = *(const frag_ab*)&Alds[(wave*16 + lrow)*40 + lk];
#pragma unroll
    for (int g = 0; g < BN/16; g++){
      frag_ab b = *(const frag_ab*)&Blds[(g*16 + lrow)*40 + lk];
      acc[g] = __builtin_amdgcn_mfma_f32_16x16x32_bf16(a, b, acc[g], 0, 0, 0);
    }
    __syncthreads();
  }

  // ---- epilogue: bias + ReLU + bf16 store (4 consecutive pixels packed) ----
  const unsigned mbase = m0 + wave*16 + ((lane >> 4) << 2);
  const unsigned nim_o = mbase / SPB;
  const unsigned spo   = mbase % SPB;
#pragma unroll
  for (int g = 0; g < BN/16; g++){
    const int ko = n0 + g*16 + (lane & 15);
    const float bv = bias[ko];
    union { unsigned short s[4]; uint2 v; } u;
#pragma unroll
    for (int r = 0; r < 4; r++) u.s[r] = f2bf(fmaxf(acc[g][r] + bv, 0.f));
    *(uint2*)(out + ((size_t)nim_o*Kout + ko)*SPB + spo) = u.v;
  }
}

// ---------------------------------------------------------------------------
// FC GEMM: A (2048 x 4096) bf16 row-major, W (256 x 4096) bf16 (= B^T),
// out fp32 feats (2048 x 256). Same tile structure, plain A rows.
// ---------------------------------------------------------------------------
__global__ void __launch_bounds__(256)
fc_mfma(const unsigned short* __restrict__ A, const unsigned short* __restrict__ wB,
        const float* __restrict__ bias, float* __restrict__ outF)
{
  constexpr int KD = 4096, BN = 64, Kout = 256;
  __shared__ __align__(16) unsigned short Alds[64*40];
  __shared__ __align__(16) unsigned short Blds[BN*40];

  const int tid  = threadIdx.x;
  const int wave = tid >> 6, lane = tid & 63;
  const int m0 = blockIdx.x * 64;
  const int n0 = blockIdx.y * BN;

  const int ar = tid >> 2, ai = tid & 3;
  const unsigned short* Asrc = A + (size_t)(m0 + ar)*KD + ai*8;
  unsigned short* Adst = &Alds[ar*40 + ai*8];
  const int bn = tid >> 2, bi = tid & 3;
  const unsigned short* Bsrc = wB + (size_t)(n0 + bn)*KD + bi*8;
  unsigned short* Bdst = &Blds[bn*40 + bi*8];

  frag_cd acc[BN/16];
#pragma unroll
  for (int g = 0; g < BN/16; g++) acc[g] = (frag_cd){0.f,0.f,0.f,0.f};

  const int lrow = lane & 15;
  const int lk   = (lane >> 4) * 8;

#pragma unroll 1
  for (int kt = 0; kt < KD/32; kt++){
    *(uint4*)Adst = *(const uint4*)(Asrc + kt*32);
    *(uint4*)Bdst = *(const uint4*)(Bsrc + kt*32);
    __syncthreads();
    frag_ab a = *(const frag_ab*)&Alds[(wave*16 + lrow)*40 + lk];
#pragma unroll
    for (int g = 0; g < BN/16; g++){
      frag_ab b = *(const frag_ab*)&Blds[(g*16 + lrow)*40 + lk];
      acc[g] = __builtin_amdgcn_mfma_f32_16x16x32_bf16(a, b, acc[g], 0, 0, 0);
    }
    __syncthreads();
  }

  const int mbase = m0 + wave*16 + ((lane >> 4) << 2);
#pragma unroll
  for (int g = 0; g < BN/16; g++){
    const int ko = n0 + g*16 + (lane & 15);
    const float bv = bias[ko];
#pragma unroll
    for (int r = 0; r < 4; r++)
      outF[(size_t)(mbase + r)*Kout + ko] = acc[g][r] + bv;
  }
}

// ---------------------------------------------------------------------------
// RSSM scan: one block per batch element, 384 threads. (unchanged from R0)
// ---------------------------------------------------------------------------
__global__ void __launch_bounds__(384)
rssm_scan(const float* __restrict__ actions, const float* __restrict__ feats,
          const float* __restrict__ eps,
          const float* __restrict__ wihT,  const float* __restrict__ whhT,
          const float* __restrict__ bih,   const float* __restrict__ bhh,
          const float* __restrict__ priorT, const float* __restrict__ prior_b,
          const float* __restrict__ postT,  const float* __restrict__ post_b,
          float* __restrict__ out)
{
  const int b   = blockIdx.x;
  const int tid = threadIdx.x;

  __shared__ float sh_h[Hn];
  __shared__ float sh_x[Ln + An];
  __shared__ float sh_f[FDn];
  __shared__ float sh_gi[3*Hn];
  __shared__ float sh_gh[3*Hn];
  __shared__ float sh_pq[64];
  __shared__ float sh_z[Ln];

  if (tid < Hn) sh_h[tid] = 0.f;
  if (tid >= Hn && tid < Hn + Ln) sh_z[tid - Hn] = 0.f;
  __syncthreads();

  const int OFF_MUP = 0;
  const int OFF_LVP = Bn*Tn*Ln;
  const int OFF_MUQ = 2*Bn*Tn*Ln;
  const int OFF_LVQ = 3*Bn*Tn*Ln;
  const int OFF_H   = 4*Bn*Tn*Ln;
  const int OFF_Z   = 4*Bn*Tn*Ln + Bn*Tn*Hn;

  for (int t = 0; t < Tn; t++){
    const int bt = b*Tn + t;
    if (tid < Ln) sh_x[tid] = sh_z[tid];
    else if (tid < Ln + An) sh_x[tid] = actions[(size_t)bt*An + (tid - Ln)];
    else if (tid >= 64 && tid < 64 + FDn) sh_f[tid - 64] = feats[(size_t)bt*FDn + (tid - 64)];
    __syncthreads();

    {
      const int i = tid;
      float gi0 = bih[i], gi1 = 0.f;
#pragma unroll
      for (int k = 0; k < Ln + An; k += 2){
        gi0 = fmaf(wihT[(k+0)*384 + i], sh_x[k+0], gi0);
        gi1 = fmaf(wihT[(k+1)*384 + i], sh_x[k+1], gi1);
      }
      float g0 = bhh[i], g1 = 0.f, g2 = 0.f, g3 = 0.f;
      for (int k = 0; k < Hn; k += 4){
        g0 = fmaf(whhT[(k+0)*384 + i], sh_h[k+0], g0);
        g1 = fmaf(whhT[(k+1)*384 + i], sh_h[k+1], g1);
        g2 = fmaf(whhT[(k+2)*384 + i], sh_h[k+2], g2);
        g3 = fmaf(whhT[(k+3)*384 + i], sh_h[k+3], g3);
      }
      sh_gi[i] = gi0 + gi1;
      sh_gh[i] = (g0 + g1) + (g2 + g3);
    }
    __syncthreads();

    float hnew = 0.f;
    if (tid < Hn){
      const float r  = sigmoidf(sh_gi[tid]      + sh_gh[tid]);
      const float zg = sigmoidf(sh_gi[Hn + tid] + sh_gh[Hn + tid]);
      const float nn = tanhf(fmaf(r, sh_gh[2*Hn + tid], sh_gi[2*Hn + tid]));
      hnew = (1.f - zg)*nn + zg*sh_h[tid];
    }
    __syncthreads();
    if (tid < Hn){
      sh_h[tid] = hnew;
      out[OFF_H + (size_t)bt*Hn + tid] = hnew;
    }
    __syncthreads();

    if (tid < 64){
      const int o = tid;
      float a0 = prior_b[o], a1 = 0.f, a2 = 0.f, a3 = 0.f;
      for (int k = 0; k < Hn; k += 4){
        a0 = fmaf(priorT[(k+0)*64 + o], sh_h[k+0], a0);
        a1 = fmaf(priorT[(k+1)*64 + o], sh_h[k+1], a1);
        a2 = fmaf(priorT[(k+2)*64 + o], sh_h[k+2], a2);
        a3 = fmaf(priorT[(k+3)*64 + o], sh_h[k+3], a3);
      }
      const float p = (a0 + a1) + (a2 + a3);
      if (o < Ln) out[OFF_MUP + (size_t)bt*Ln + o] = p;
      else        out[OFF_LVP + (size_t)bt*Ln + (o - Ln)] = p;
    } else if (tid < 128){
      const int o = tid - 64;
      float a0 = post_b[o], a1 = 0.f, a2 = 0.f, a3 = 0.f;
      for (int k = 0; k < Hn; k += 4){
        a0 = fmaf(postT[(k+0)*64 + o], sh_h[k+0], a0);
        a1 = fmaf(postT[(k+1)*64 + o], sh_h[k+1], a1);
        a2 = fmaf(postT[(k+2)*64 + o], sh_h[k+2], a2);
        a3 = fmaf(postT[(k+3)*64 + o], sh_h[k+3], a3);
      }
      for (int k = 0; k < FDn; k += 4){
        a0 = fmaf(postT[(Hn+k+0)*64 + o], sh_f[k+0], a0);
        a1 = fmaf(postT[(Hn+k+1)*64 + o], sh_f[k+1], a1);
        a2 = fmaf(postT[(Hn+k+2)*64 + o], sh_f[k+2], a2);
        a3 = fmaf(postT[(Hn+k+3)*64 + o], sh_f[k+3], a3);
      }
      const float q = (a0 + a1) + (a2 + a3);
      sh_pq[o] = q;
      if (o < Ln) out[OFF_MUQ + (size_t)bt*Ln + o] = q;
      else        out[OFF_LVQ + (size_t)bt*Ln + (o - Ln)] = q;
    }
    __syncthreads();

    if (tid < Ln){
      const float mu = sh_pq[tid], lv = sh_pq[Ln + tid];
      const float zz = fmaf(expf(0.5f*lv), eps[(size_t)bt*Ln + tid], mu);
      sh_z[tid] = zz;
      out[OFF_Z + (size_t)bt*Ln + tid] = zz;
    }
    __syncthreads();
  }
}

// ---------------------------------------------------------------------------
extern "C" void kernel_launch(void* const* d_in, const int* in_sizes, int n_in,
                              void* d_out, int out_size, void* d_ws, size_t ws_size,
                              hipStream_t stream)
{
  const float* states = (const float*)d_in[0];
  const float* actions= (const float*)d_in[1];
  const float* c1_w = (const float*)d_in[2];  const float* c1_b = (const float*)d_in[3];
  const float* c2_w = (const float*)d_in[4];  const float* c2_b = (const float*)d_in[5];
  const float* c3_w = (const float*)d_in[6];  const float* c3_b = (const float*)d_in[7];
  const float* c4_w = (const float*)d_in[8];  const float* c4_b = (const float*)d_in[9];
  const float* fc_w = (const float*)d_in[10]; const float* fc_b = (const float*)d_in[11];
  const float* gwih = (const float*)d_in[12]; const float* gwhh = (const float*)d_in[13];
  const float* gbih = (const float*)d_in[14]; const float* gbhh = (const float*)d_in[15];
  const float* pr_w = (const float*)d_in[16]; const float* pr_b = (const float*)d_in[17];
  const float* po_w = (const float*)d_in[18]; const float* po_b = (const float*)d_in[19];
  const float* eps  = (const float*)d_in[20];

  char* p = (char*)d_ws;
  auto alloc = [&](size_t bytes){ char* r = p; p += (bytes + 255) & ~255ULL; return r; };

  unsigned short* statesB = (unsigned short*)alloc((size_t)Nimg*3*64*64*2);
  unsigned short* act1    = (unsigned short*)alloc((size_t)Nimg*32*1024*2);
  unsigned short* act2    = (unsigned short*)alloc((size_t)Nimg*64*256*2);
  unsigned short* act3    = (unsigned short*)alloc((size_t)Nimg*128*64*2);
  unsigned short* act4    = (unsigned short*)alloc((size_t)Nimg*256*16*2);
  float*          feats   = (float*)alloc((size_t)Nimg*FDn*4);
  unsigned short* w1b     = (unsigned short*)alloc(32*64*2);
  unsigned short* w2b     = (unsigned short*)alloc(64*512*2);
  unsigned short* w3b     = (unsigned short*)alloc((size_t)128*1024*2);
  unsigned short* w4b     = (unsigned short*)alloc((size_t)256*2048*2);
  unsigned short* wfcb    = (unsigned short*)alloc((size_t)256*4096*2);
  float* wihT   = (float*)alloc(38*384*4);
  float* whhT   = (float*)alloc(128*384*4);
  float* priorT = (float*)alloc(128*64*4);
  float* postT  = (float*)alloc(384*64*4);

  // --- weight/input conversions (idempotent each call) ---
  {
    int n = Nimg*3*64*64;
    f2bf_kernel<<<(n/4+255)/256, 256, 0, stream>>>(states, statesB, n);
  }
  conv1w_kernel<<<8, 256, 0, stream>>>(c1_w, w1b);
  f2bf_kernel<<<(64*512/4+255)/256, 256, 0, stream>>>(c2_w, w2b, 64*512);
  f2bf_kernel<<<(128*1024/4+255)/256, 256, 0, stream>>>(c3_w, w3b, 128*1024);
  f2bf_kernel<<<(256*2048/4+255)/256, 256, 0, stream>>>(c4_w, w4b, 256*2048);
  f2bf_kernel<<<(256*4096/4+255)/256, 256, 0, stream>>>(fc_w, wfcb, 256*4096);

  transpose_kernel<<<(384*38  +255)/256, 256, 0, stream>>>(gwih, wihT, 384, 38);
  transpose_kernel<<<(384*128 +255)/256, 256, 0, stream>>>(gwhh, whhT, 384, 128);
  transpose_kernel<<<(64*128  +255)/256, 256, 0, stream>>>(pr_w, priorT, 64, 128);
  transpose_kernel<<<(64*384  +255)/256, 256, 0, stream>>>(po_w, postT, 64, 384);

  // --- encoder: implicit-GEMM MFMA convs ---
  conv_mfma<4,3,64,32,32,32>   <<< dim3(Nimg*1024/64, 1), 256, 0, stream >>>(statesB, w1b, c1_b, act1);
  conv_mfma<32,32,32,64,16,64> <<< dim3(Nimg*256/64, 1), 256, 0, stream >>>(act1, w2b, c2_b, act2);
  conv_mfma<64,64,16,128,8,64> <<< dim3(Nimg*64/64, 2), 256, 0, stream >>>(act2, w3b, c3_b, act3);
  conv_mfma<128,128,8,256,4,64><<< dim3(Nimg*16/64, 4), 256, 0, stream >>>(act3, w4b, c4_b, act4);

  fc_mfma<<< dim3(Nimg/64, 4), 256, 0, stream >>>(act4, wfcb, fc_b, feats);

  rssm_scan<<< Bn, 384, 0, stream >>>(actions, feats, eps, wihT, whhT, gbih, gbhh,
                                      priorT, pr_b, postT, po_b, (float*)d_out);
}

// Round 3
// 992.869 us; speedup vs baseline: 18.4092x; 2.6138x over previous
//
#include <hip/hip_runtime.h>
#include <math.h>

#define Bn 32
#define Tn 64
#define An 6
#define Ln 32
#define Hn 128
#define FDn 256
#define Nimg (Bn*Tn)   // 2048

typedef __attribute__((ext_vector_type(8))) short frag_ab;   // 8 bf16
typedef __attribute__((ext_vector_type(4))) float frag_cd;   // 4 fp32

__device__ __forceinline__ float sigmoidf(float x){ return 1.f/(1.f + expf(-x)); }

__device__ __forceinline__ unsigned short f2bf(float f){
  unsigned int u = __float_as_uint(f);
  unsigned int r = (u + 0x7fffu + ((u >> 16) & 1u)) >> 16;
  return (unsigned short)r;
}
__device__ __forceinline__ unsigned pack2(float a, float b){
  return (unsigned)f2bf(a) | ((unsigned)f2bf(b) << 16);
}
__device__ __forceinline__ float bf_lo(unsigned u){ return __uint_as_float(u << 16); }
__device__ __forceinline__ float bf_hi(unsigned u){ return __uint_as_float(u & 0xffff0000u); }

// ---------------------------------------------------------------------------
// fp32 -> bf16 conversion, 4 elems/thread (n divisible by 4)
// ---------------------------------------------------------------------------
__global__ void __launch_bounds__(256)
f2bf_kernel(const float* __restrict__ src, unsigned short* __restrict__ dst, int n)
{
  int i = (blockIdx.x * blockDim.x + threadIdx.x) * 4;
  if (i < n){
    float4 f = *(const float4*)(src + i);
    union { unsigned short s[4]; uint2 v; } u;
    u.s[0]=f2bf(f.x); u.s[1]=f2bf(f.y); u.s[2]=f2bf(f.z); u.s[3]=f2bf(f.w);
    *(uint2*)(dst + i) = u.v;
  }
}

// conv1 weights: (32,3,4,4) fp32 -> (32,4,16) bf16 with channel 3 zero-padded
__global__ void __launch_bounds__(256)
conv1w_kernel(const float* __restrict__ src, unsigned short* __restrict__ dst)
{
  int i = blockIdx.x * blockDim.x + threadIdx.x;   // 32*64
  if (i < 32*64){
    int k = i >> 6, r = i & 63;
    int c = r >> 4, tap = r & 15;
    dst[i] = (c < 3) ? f2bf(src[(k*3 + c)*16 + tap]) : (unsigned short)0;
  }
}

// ---------------------------------------------------------------------------
// Scan weight packing (bf16 pairs).
// ---------------------------------------------------------------------------
#define SCAN_WHH_U  (64*384)          // whh2[k2][i]
#define SCAN_POST_PAD 195
#define SCAN_POST_U (64*SCAN_POST_PAD) // post2[o][k2], 192 used, pad->195
#define SCAN_U      (SCAN_WHH_U + SCAN_POST_U)   // 37056 uints = 148224 B

__global__ void __launch_bounds__(256)
pack_whh_kernel(const float* __restrict__ g, unsigned* __restrict__ dst)
{ // g: (384,128) row-major -> dst[k2*384+i]
  int idx = blockIdx.x*256 + threadIdx.x;
  if (idx < 64*384){
    int k2 = idx / 384, i = idx - k2*384;
    dst[idx] = pack2(g[i*128 + 2*k2], g[i*128 + 2*k2 + 1]);
  }
}
__global__ void __launch_bounds__(256)
pack_post_kernel(const float* __restrict__ g, unsigned* __restrict__ dst)
{ // g: (64,384) row-major -> dst[o*195 + k2], k2<192
  int idx = blockIdx.x*256 + threadIdx.x;
  if (idx < 64*192){
    int o = idx / 192, k2 = idx - o*192;
    dst[o*SCAN_POST_PAD + k2] = pack2(g[o*384 + 2*k2], g[o*384 + 2*k2 + 1]);
  }
}
__global__ void __launch_bounds__(256)
pack_prior_kernel(const float* __restrict__ g, unsigned* __restrict__ dst)
{ // g: (64,128) -> dst[o*64 + k2]
  int idx = blockIdx.x*256 + threadIdx.x;
  if (idx < 64*64){
    int o = idx >> 6, k2 = idx & 63;
    dst[idx] = pack2(g[o*128 + 2*k2], g[o*128 + 2*k2 + 1]);
  }
}
__global__ void __launch_bounds__(256)
pack_wih_kernel(const float* __restrict__ g, unsigned* __restrict__ dst)
{ // g: (384,38) -> dst[k2*384 + i], k2<19
  int idx = blockIdx.x*256 + threadIdx.x;
  if (idx < 19*384){
    int k2 = idx / 384, i = idx - k2*384;
    dst[idx] = pack2(g[i*38 + 2*k2], g[i*38 + 2*k2 + 1]);
  }
}

// ---------------------------------------------------------------------------
// Implicit-GEMM conv (k=4, s=2, p=1) on MFMA 16x16x32 bf16. (unchanged R1)
// ---------------------------------------------------------------------------
template<int Cin, int CinReal, int IN, int Kout, int OUT, int BN>
__global__ void __launch_bounds__(256)
conv_mfma(const unsigned short* __restrict__ in, const unsigned short* __restrict__ wB,
          const float* __restrict__ bias, unsigned short* __restrict__ out)
{
  constexpr int SPB = OUT*OUT;
  constexpr int KD  = Cin*16;
  __shared__ __align__(16) unsigned short Alds[64*40];
  __shared__ __align__(16) unsigned short Blds[BN*40];

  const int tid  = threadIdx.x;
  const int wave = tid >> 6, lane = tid & 63;
  const unsigned m0 = blockIdx.x * 64;
  const int n0 = blockIdx.y * BN;

  const int ar  = tid >> 2;
  const int aq  = tid & 3;
  const int c2  = aq >> 1;
  const int kh0 = (aq & 1) * 2;
  const unsigned m   = m0 + ar;
  const unsigned nim = m / SPB;
  const unsigned sp  = m % SPB;
  const int oy = sp / OUT, ox = sp % OUT;
  const int ix0 = ox*2 - 1;
  const unsigned short* inN = in + (size_t)nim * CinReal * IN * IN;
  int  iyoff[2]; bool iyok[2];
#pragma unroll
  for (int dh = 0; dh < 2; dh++){
    int iy = oy*2 - 1 + kh0 + dh;
    iyok[dh]  = (iy >= 0 && iy < IN);
    iyoff[dh] = iyok[dh] ? iy*IN : 0;
  }
  bool ixok[4];
#pragma unroll
  for (int kw = 0; kw < 4; kw++) ixok[kw] = (ix0+kw >= 0 && ix0+kw < IN);
  unsigned short* Adst = &Alds[ar*40 + c2*16 + kh0*4];

  const int bn = tid >> 2;
  const int bi = tid & 3;
  const unsigned short* Bsrc = wB + (size_t)(n0 + bn)*KD + bi*8;
  unsigned short* Bdst = &Blds[bn*40 + bi*8];

  frag_cd acc[BN/16];
#pragma unroll
  for (int g = 0; g < BN/16; g++) acc[g] = (frag_cd){0.f,0.f,0.f,0.f};

  const int lrow = lane & 15;
  const int lk   = (lane >> 4) * 8;

#pragma unroll 1
  for (int kt = 0; kt < KD/32; kt++){
    {
      union { unsigned short s[8]; uint4 v; } va;
#pragma unroll
      for (int j = 0; j < 8; j++) va.s[j] = 0;
      const int c = kt*2 + c2;
      if (Cin == CinReal || c < CinReal){
        const unsigned short* ip = inN + (size_t)c * IN * IN;
#pragma unroll
        for (int dh = 0; dh < 2; dh++){
          if (iyok[dh]){
#pragma unroll
            for (int kw = 0; kw < 4; kw++)
              if (ixok[kw]) va.s[dh*4+kw] = ip[iyoff[dh] + ix0 + kw];
          }
        }
      }
      *(uint4*)Adst = va.v;
    }
    if (tid < BN*4)
      *(uint4*)Bdst = *(const uint4*)(Bsrc + kt*32);
    __syncthreads();

    frag_ab a = *(const frag_ab*)&Alds[(wave*16 + lrow)*40 + lk];
#pragma unroll
    for (int g = 0; g < BN/16; g++){
      frag_ab b = *(const frag_ab*)&Blds[(g*16 + lrow)*40 + lk];
      acc[g] = __builtin_amdgcn_mfma_f32_16x16x32_bf16(a, b, acc[g], 0, 0, 0);
    }
    __syncthreads();
  }

  const unsigned mbase = m0 + wave*16 + ((lane >> 4) << 2);
  const unsigned nim_o = mbase / SPB;
  const unsigned spo   = mbase % SPB;
#pragma unroll
  for (int g = 0; g < BN/16; g++){
    const int ko = n0 + g*16 + (lane & 15);
    const float bv = bias[ko];
    union { unsigned short s[4]; uint2 v; } u;
#pragma unroll
    for (int r = 0; r < 4; r++) u.s[r] = f2bf(fmaxf(acc[g][r] + bv, 0.f));
    *(uint2*)(out + ((size_t)nim_o*Kout + ko)*SPB + spo) = u.v;
  }
}

// ---------------------------------------------------------------------------
// FC GEMM (unchanged R1): A (2048x4096) bf16, W (256x4096) bf16, out fp32.
// ---------------------------------------------------------------------------
__global__ void __launch_bounds__(256)
fc_mfma(const unsigned short* __restrict__ A, const unsigned short* __restrict__ wB,
        const float* __restrict__ bias, float* __restrict__ outF)
{
  constexpr int KD = 4096, BN = 64, Kout = 256;
  __shared__ __align__(16) unsigned short Alds[64*40];
  __shared__ __align__(16) unsigned short Blds[BN*40];

  const int tid  = threadIdx.x;
  const int wave = tid >> 6, lane = tid & 63;
  const int m0 = blockIdx.x * 64;
  const int n0 = blockIdx.y * BN;

  const int ar = tid >> 2, ai = tid & 3;
  const unsigned short* Asrc = A + (size_t)(m0 + ar)*KD + ai*8;
  unsigned short* Adst = &Alds[ar*40 + ai*8];
  const int bn = tid >> 2, bi = tid & 3;
  const unsigned short* Bsrc = wB + (size_t)(n0 + bn)*KD + bi*8;
  unsigned short* Bdst = &Blds[bn*40 + bi*8];

  frag_cd acc[BN/16];
#pragma unroll
  for (int g = 0; g < BN/16; g++) acc[g] = (frag_cd){0.f,0.f,0.f,0.f};

  const int lrow = lane & 15;
  const int lk   = (lane >> 4) * 8;

#pragma unroll 1
  for (int kt = 0; kt < KD/32; kt++){
    *(uint4*)Adst = *(const uint4*)(Asrc + kt*32);
    *(uint4*)Bdst = *(const uint4*)(Bsrc + kt*32);
    __syncthreads();
    frag_ab a = *(const frag_ab*)&Alds[(wave*16 + lrow)*40 + lk];
#pragma unroll
    for (int g = 0; g < BN/16; g++){
      frag_ab b = *(const frag_ab*)&Blds[(g*16 + lrow)*40 + lk];
      acc[g] = __builtin_amdgcn_mfma_f32_16x16x32_bf16(a, b, acc[g], 0, 0, 0);
    }
    __syncthreads();
  }

  const int mbase = m0 + wave*16 + ((lane >> 4) << 2);
#pragma unroll
  for (int g = 0; g < BN/16; g++){
    const int ko = n0 + g*16 + (lane & 15);
    const float bv = bias[ko];
#pragma unroll
    for (int r = 0; r < 4; r++)
      outF[(size_t)(mbase + r)*Kout + ko] = acc[g][r] + bv;
  }
}

// ---------------------------------------------------------------------------
// RSSM scan v2: weights resident (whh/post bf16-pairs in LDS, wih/prior in
// registers). 1 block / batch, 384 threads, 4 barriers/step.
//   phase A: thread i computes gate i (gi over 38, gh over 128)
//   phase B: threads 0..127: prior (2/out, k-split 64); 128..383: post (4/out,
//            k-split 96), shfl_xor combine.
// ---------------------------------------------------------------------------
__global__ void __launch_bounds__(384)
rssm_scan2(const float* __restrict__ actions, const float* __restrict__ feats,
           const float* __restrict__ eps,
           const unsigned* __restrict__ g_scan,   // whh2 ++ post2 (SCAN_U)
           const unsigned* __restrict__ g_wih2,   // [19][384]
           const unsigned* __restrict__ g_pr2,    // [64][64]
           const float* __restrict__ bih,  const float* __restrict__ bhh,
           const float* __restrict__ prior_b, const float* __restrict__ post_b,
           float* __restrict__ out)
{
  __shared__ __align__(16) unsigned lds_w[SCAN_U];
  __shared__ __align__(16) float sh_hf[384];   // [0,128)=h, [128,384)=f
  __shared__ __align__(16) float sh_x[40];     // [0,32)=z, [32,38)=a
  __shared__ float sh_gi[384];
  __shared__ float sh_gh[384];
  __shared__ float sh_pq[64];

  const int b = blockIdx.x, tid = threadIdx.x;

  // one-time: stage packed weights into LDS (uint4, both 16B aligned)
  for (int i = tid; i < SCAN_U/4; i += 384)
    ((uint4*)lds_w)[i] = ((const uint4*)g_scan)[i];

  unsigned wih[19];
#pragma unroll
  for (int c = 0; c < 19; c++) wih[c] = g_wih2[c*384 + tid];

  unsigned prw[32];
  if (tid < 128){
    const unsigned* src = g_pr2 + (tid >> 1)*64 + (tid & 1)*32;
#pragma unroll
    for (int c = 0; c < 32; c++) prw[c] = src[c];
  }

  const float bih_i = bih[tid], bhh_i = bhh[tid];

  if (tid < 128) sh_hf[tid] = 0.f;
  if (tid < 40)  sh_x[tid] = 0.f;
  __syncthreads();

  const unsigned* whh2  = lds_w;               // [k2][384]
  const unsigned* post2 = lds_w + SCAN_WHH_U;  // [o][195]

  const int OFF_MUP = 0;
  const int OFF_LVP = Bn*Tn*Ln;
  const int OFF_MUQ = 2*Bn*Tn*Ln;
  const int OFF_LVQ = 3*Bn*Tn*Ln;
  const int OFF_H   = 4*Bn*Tn*Ln;
  const int OFF_Z   = 4*Bn*Tn*Ln + Bn*Tn*Hn;

  for (int t = 0; t < Tn; t++){
    const int bt = b*Tn + t;
    // stage a_t and f_t (z already in sh_x from previous step)
    if (tid >= 32 && tid < 38) sh_x[tid] = actions[(size_t)bt*An + (tid - 32)];
    if (tid >= 64 && tid < 320) sh_hf[128 + tid - 64] = feats[(size_t)bt*FDn + (tid - 64)];
    __syncthreads();   // B1

    // ---- phase A: gates ----
    {
      float a0 = bih_i, a1 = 0.f;
      const float2* x2 = (const float2*)sh_x;
#pragma unroll
      for (int c = 0; c < 19; c++){
        float2 xv = x2[c];
        a0 = fmaf(bf_lo(wih[c]), xv.x, a0);
        a1 = fmaf(bf_hi(wih[c]), xv.y, a1);
      }
      sh_gi[tid] = a0 + a1;

      float g0 = bhh_i, g1 = 0.f, g2 = 0.f, g3 = 0.f;
      const float4* h4 = (const float4*)sh_hf;
#pragma unroll
      for (int k4 = 0; k4 < 32; k4++){
        float4 hv = h4[k4];
        unsigned u0 = whh2[(2*k4  )*384 + tid];
        unsigned u1 = whh2[(2*k4+1)*384 + tid];
        g0 = fmaf(bf_lo(u0), hv.x, g0);
        g1 = fmaf(bf_hi(u0), hv.y, g1);
        g2 = fmaf(bf_lo(u1), hv.z, g2);
        g3 = fmaf(bf_hi(u1), hv.w, g3);
      }
      sh_gh[tid] = (g0 + g1) + (g2 + g3);
    }
    __syncthreads();   // B2

    // ---- GRU combine ----
    if (tid < Hn){
      const float r  = sigmoidf(sh_gi[tid]       + sh_gh[tid]);
      const float zg = sigmoidf(sh_gi[Hn  + tid] + sh_gh[Hn  + tid]);
      const float nn = tanhf(fmaf(r, sh_gh[2*Hn + tid], sh_gi[2*Hn + tid]));
      const float hnew = (1.f - zg)*nn + zg*sh_hf[tid];
      sh_hf[tid] = hnew;
      out[OFF_H + (size_t)bt*Hn + tid] = hnew;
    }
    __syncthreads();   // B3

    // ---- phase B: prior / posterior ----
    if (tid < 128){
      const int j = tid & 1;                       // k-split half
      const float4* h4 = (const float4*)(sh_hf + j*64);
      float a0 = 0.f, a1 = 0.f, a2 = 0.f, a3 = 0.f;
#pragma unroll
      for (int c4 = 0; c4 < 16; c4++){
        float4 hv = h4[c4];
        unsigned u0 = prw[2*c4], u1 = prw[2*c4+1];
        a0 = fmaf(bf_lo(u0), hv.x, a0);
        a1 = fmaf(bf_hi(u0), hv.y, a1);
        a2 = fmaf(bf_lo(u1), hv.z, a2);
        a3 = fmaf(bf_hi(u1), hv.w, a3);
      }
      float p = (a0 + a1) + (a2 + a3);
      p += __shfl_xor(p, 1);
      if (j == 0){
        const int o = tid >> 1;
        p += prior_b[o];
        if (o < Ln) out[OFF_MUP + (size_t)bt*Ln + o] = p;
        else        out[OFF_LVP + (size_t)bt*Ln + (o - Ln)] = p;
      }
    } else {
      const int tt = tid - 128;
      const int o = tt >> 2, j = tt & 3;           // k-split quarter (96 each)
      const float4* h4 = (const float4*)(sh_hf + j*96);
      const unsigned* pw = post2 + o*SCAN_POST_PAD + j*48;
      float a0 = 0.f, a1 = 0.f, a2 = 0.f, a3 = 0.f;
#pragma unroll
      for (int c4 = 0; c4 < 24; c4++){
        float4 hv = h4[c4];
        unsigned u0 = pw[2*c4], u1 = pw[2*c4+1];
        a0 = fmaf(bf_lo(u0), hv.x, a0);
        a1 = fmaf(bf_hi(u0), hv.y, a1);
        a2 = fmaf(bf_lo(u1), hv.z, a2);
        a3 = fmaf(bf_hi(u1), hv.w, a3);
      }
      float p = (a0 + a1) + (a2 + a3);
      p += __shfl_xor(p, 1);
      p += __shfl_xor(p, 2);
      if (j == 0){
        p += post_b[o];
        sh_pq[o] = p;
        if (o < Ln) out[OFF_MUQ + (size_t)bt*Ln + o] = p;
        else        out[OFF_LVQ + (size_t)bt*Ln + (o - Ln)] = p;
      }
    }
    __syncthreads();   // B4

    // ---- reparameterize: z -> sh_x[0..32) for next step ----
    if (tid < Ln){
      const float mu = sh_pq[tid], lv = sh_pq[Ln + tid];
      const float zz = fmaf(expf(0.5f*lv), eps[(size_t)bt*Ln + tid], mu);
      sh_x[tid] = zz;
      out[OFF_Z + (size_t)bt*Ln + tid] = zz;
    }
    // no barrier needed: next-step B1 orders sh_x/sh_pq accesses
  }
}

// ---------------------------------------------------------------------------
extern "C" void kernel_launch(void* const* d_in, const int* in_sizes, int n_in,
                              void* d_out, int out_size, void* d_ws, size_t ws_size,
                              hipStream_t stream)
{
  const float* states = (const float*)d_in[0];
  const float* actions= (const float*)d_in[1];
  const float* c1_w = (const float*)d_in[2];  const float* c1_b = (const float*)d_in[3];
  const float* c2_w = (const float*)d_in[4];  const float* c2_b = (const float*)d_in[5];
  const float* c3_w = (const float*)d_in[6];  const float* c3_b = (const float*)d_in[7];
  const float* c4_w = (const float*)d_in[8];  const float* c4_b = (const float*)d_in[9];
  const float* fc_w = (const float*)d_in[10]; const float* fc_b = (const float*)d_in[11];
  const float* gwih = (const float*)d_in[12]; const float* gwhh = (const float*)d_in[13];
  const float* gbih = (const float*)d_in[14]; const float* gbhh = (const float*)d_in[15];
  const float* pr_w = (const float*)d_in[16]; const float* pr_b = (const float*)d_in[17];
  const float* po_w = (const float*)d_in[18]; const float* po_b = (const float*)d_in[19];
  const float* eps  = (const float*)d_in[20];

  char* p = (char*)d_ws;
  auto alloc = [&](size_t bytes){ char* r = p; p += (bytes + 255) & ~255ULL; return r; };

  unsigned short* statesB = (unsigned short*)alloc((size_t)Nimg*3*64*64*2);
  unsigned short* act1    = (unsigned short*)alloc((size_t)Nimg*32*1024*2);
  unsigned short* act2    = (unsigned short*)alloc((size_t)Nimg*64*256*2);
  unsigned short* act3    = (unsigned short*)alloc((size_t)Nimg*128*64*2);
  unsigned short* act4    = (unsigned short*)alloc((size_t)Nimg*256*16*2);
  float*          feats   = (float*)alloc((size_t)Nimg*FDn*4);
  unsigned short* w1b     = (unsigned short*)alloc(32*64*2);
  unsigned short* w2b     = (unsigned short*)alloc(64*512*2);
  unsigned short* w3b     = (unsigned short*)alloc((size_t)128*1024*2);
  unsigned short* w4b     = (unsigned short*)alloc((size_t)256*2048*2);
  unsigned short* wfcb    = (unsigned short*)alloc((size_t)256*4096*2);
  unsigned* g_scan = (unsigned*)alloc((size_t)SCAN_U*4);
  unsigned* g_wih2 = (unsigned*)alloc((size_t)19*384*4);
  unsigned* g_pr2  = (unsigned*)alloc((size_t)64*64*4);

  // --- conversions / packing (idempotent each call) ---
  {
    int n = Nimg*3*64*64;
    f2bf_kernel<<<(n/4+255)/256, 256, 0, stream>>>(states, statesB, n);
  }
  conv1w_kernel<<<8, 256, 0, stream>>>(c1_w, w1b);
  f2bf_kernel<<<(64*512/4+255)/256, 256, 0, stream>>>(c2_w, w2b, 64*512);
  f2bf_kernel<<<(128*1024/4+255)/256, 256, 0, stream>>>(c3_w, w3b, 128*1024);
  f2bf_kernel<<<(256*2048/4+255)/256, 256, 0, stream>>>(c4_w, w4b, 256*2048);
  f2bf_kernel<<<(256*4096/4+255)/256, 256, 0, stream>>>(fc_w, wfcb, 256*4096);

  pack_whh_kernel  <<<(64*384 +255)/256, 256, 0, stream>>>(gwhh, g_scan);
  pack_post_kernel <<<(64*192 +255)/256, 256, 0, stream>>>(po_w, g_scan + SCAN_WHH_U);
  pack_prior_kernel<<<(64*64  +255)/256, 256, 0, stream>>>(pr_w, g_pr2);
  pack_wih_kernel  <<<(19*384 +255)/256, 256, 0, stream>>>(gwih, g_wih2);

  // --- encoder: implicit-GEMM MFMA convs ---
  conv_mfma<4,3,64,32,32,32>   <<< dim3(Nimg*1024/64, 1), 256, 0, stream >>>(statesB, w1b, c1_b, act1);
  conv_mfma<32,32,32,64,16,64> <<< dim3(Nimg*256/64, 1), 256, 0, stream >>>(act1, w2b, c2_b, act2);
  conv_mfma<64,64,16,128,8,64> <<< dim3(Nimg*64/64, 2), 256, 0, stream >>>(act2, w3b, c3_b, act3);
  conv_mfma<128,128,8,256,4,64><<< dim3(Nimg*16/64, 4), 256, 0, stream >>>(act3, w4b, c4_b, act4);

  fc_mfma<<< dim3(Nimg/64, 4), 256, 0, stream >>>(act4, wfcb, fc_b, feats);

  rssm_scan2<<< Bn, 384, 0, stream >>>(actions, feats, eps,
                                       g_scan, g_wih2, g_pr2,
                                       gbih, gbhh, pr_b, po_b, (float*)d_out);
}

// Round 4
// 847.889 us; speedup vs baseline: 21.5570x; 1.1710x over previous
//
#include <hip/hip_runtime.h>
#include <math.h>

#define Bn 32
#define Tn 64
#define An 6
#define Ln 32
#define Hn 128
#define FDn 256
#define Nimg (Bn*Tn)   // 2048

typedef __attribute__((ext_vector_type(8))) short frag_ab;   // 8 bf16
typedef __attribute__((ext_vector_type(4))) float frag_cd;   // 4 fp32
typedef _Float16 h2_t __attribute__((ext_vector_type(2)));

__device__ __forceinline__ float sigmoidf(float x){ return 1.f/(1.f + expf(-x)); }

__device__ __forceinline__ unsigned short f2bf(float f){
  unsigned int u = __float_as_uint(f);
  unsigned int r = (u + 0x7fffu + ((u >> 16) & 1u)) >> 16;
  return (unsigned short)r;
}
__device__ __forceinline__ unsigned packh(float a, float b){
  union { h2_t h; unsigned u; } x;
  x.h = (h2_t){(_Float16)a, (_Float16)b};
  return x.u;
}
__device__ __forceinline__ float fdot2u(unsigned a, unsigned b, float c){
  union { unsigned u; h2_t h; } ua, ub;
  ua.u = a; ub.u = b;
#if __has_builtin(__builtin_amdgcn_fdot2)
  return __builtin_amdgcn_fdot2(ua.h, ub.h, c, false);
#else
  return c + (float)ua.h.x*(float)ub.h.x + (float)ua.h.y*(float)ub.h.y;
#endif
}
// barrier without vmcnt drain: global stores in-flight are never read in-kernel
#define BAR_LDS() asm volatile("s_waitcnt lgkmcnt(0)\n\ts_barrier" ::: "memory")

// ---------------------------------------------------------------------------
// fp32 -> bf16 conversion, 4 elems/thread
// ---------------------------------------------------------------------------
__global__ void __launch_bounds__(256)
f2bf_kernel(const float* __restrict__ src, unsigned short* __restrict__ dst, int n)
{
  int i = (blockIdx.x * blockDim.x + threadIdx.x) * 4;
  if (i < n){
    float4 f = *(const float4*)(src + i);
    union { unsigned short s[4]; uint2 v; } u;
    u.s[0]=f2bf(f.x); u.s[1]=f2bf(f.y); u.s[2]=f2bf(f.z); u.s[3]=f2bf(f.w);
    *(uint2*)(dst + i) = u.v;
  }
}

// ---------------------------------------------------------------------------
// Scan weight image layout (f16 pairs, uints):
//   [0, 24576)            whh4: [k8][384] uint4 (k8<16)
//   [24576, 24576+13568)  po4 : [o][53] uint4 rows, entry o*53 + j*13 + kk (kk<12)
#define WHH4_U 24576
#define PO4_U  (64*53*4)       // 13568
#define SCAN_U (WHH4_U + PO4_U) // 38144 uints = 152576 B

// one merged prep kernel: conv weight bf16 conversions + scan f16 packs
__global__ void __launch_bounds__(256)
prep_kernel(const float* __restrict__ c2w, const float* __restrict__ c3w,
            const float* __restrict__ c4w, const float* __restrict__ fcw,
            const float* __restrict__ c1w,
            const float* __restrict__ gwhh, const float* __restrict__ gwih,
            const float* __restrict__ prw,  const float* __restrict__ pow_,
            unsigned short* __restrict__ w2b, unsigned short* __restrict__ w3b,
            unsigned short* __restrict__ w4b, unsigned short* __restrict__ wfcb,
            unsigned short* __restrict__ w1b,
            unsigned* __restrict__ g_scan, unsigned* __restrict__ g_wih2,
            unsigned* __restrict__ g_pr2)
{
  const int bid = blockIdx.x, tid = threadIdx.x;
  if (bid < 32){                       // c2: 32768 elems
    int i = (bid*256 + tid)*4;
    float4 f = *(const float4*)(c2w + i);
    union { unsigned short s[4]; uint2 v; } u;
    u.s[0]=f2bf(f.x); u.s[1]=f2bf(f.y); u.s[2]=f2bf(f.z); u.s[3]=f2bf(f.w);
    *(uint2*)(w2b + i) = u.v;
  } else if (bid < 160){               // c3: 131072
    int i = ((bid-32)*256 + tid)*4;
    float4 f = *(const float4*)(c3w + i);
    union { unsigned short s[4]; uint2 v; } u;
    u.s[0]=f2bf(f.x); u.s[1]=f2bf(f.y); u.s[2]=f2bf(f.z); u.s[3]=f2bf(f.w);
    *(uint2*)(w3b + i) = u.v;
  } else if (bid < 672){               // c4: 524288
    int i = ((bid-160)*256 + tid)*4;
    float4 f = *(const float4*)(c4w + i);
    union { unsigned short s[4]; uint2 v; } u;
    u.s[0]=f2bf(f.x); u.s[1]=f2bf(f.y); u.s[2]=f2bf(f.z); u.s[3]=f2bf(f.w);
    *(uint2*)(w4b + i) = u.v;
  } else if (bid < 1696){              // fc: 1048576
    int i = ((bid-672)*256 + tid)*4;
    float4 f = *(const float4*)(fcw + i);
    union { unsigned short s[4]; uint2 v; } u;
    u.s[0]=f2bf(f.x); u.s[1]=f2bf(f.y); u.s[2]=f2bf(f.z); u.s[3]=f2bf(f.w);
    *(uint2*)(wfcb + i) = u.v;
  } else if (bid < 1704){              // conv1 weights: (32,3,16)->(32,4,16) pad
    int i = (bid-1696)*256 + tid;      // < 2048
    int k = i >> 6, r = i & 63, c = r >> 4, tap = r & 15;
    w1b[i] = (c < 3) ? f2bf(c1w[(k*3 + c)*16 + tap]) : (unsigned short)0;
  } else if (bid < 1800){              // whh pack: 24576 uints
    int idx = (bid-1704)*256 + tid;
    int q = idx & 3, r = idx >> 2;
    int k8 = r / 384, i = r - k8*384;
    int k = 8*k8 + 2*q;
    g_scan[idx] = packh(gwhh[i*128 + k], gwhh[i*128 + k + 1]);
  } else if (bid < 1829){              // wih pack: 7296 uints
    int idx = (bid-1800)*256 + tid;
    if (idx < 19*384){
      int c = idx / 384, i = idx - c*384;
      g_wih2[idx] = packh(gwih[i*38 + 2*c], gwih[i*38 + 2*c + 1]);
    }
  } else if (bid < 1845){              // prior pack: 4096 uints
    int idx = (bid-1829)*256 + tid;
    int o = idx >> 6, c = idx & 63;
    g_pr2[idx] = packh(prw[o*128 + 2*c], prw[o*128 + 2*c + 1]);
  } else {                             // post pack: 12288 written entries
    int idx = (bid-1845)*256 + tid;
    if (idx < 64*192){
      int o = idx / 192, r = idx - o*192;
      int u = r >> 2, q = r & 3;
      int j = u / 12, kk = u - j*12;
      int k = 96*j + 8*kk + 2*q;
      g_scan[WHH4_U + (o*53 + j*13 + kk)*4 + q] =
        packh(pow_[o*384 + k], pow_[o*384 + k + 1]);
    }
  }
}

// ---------------------------------------------------------------------------
// Implicit-GEMM conv (k=4, s=2, p=1) on MFMA 16x16x32 bf16. (unchanged R2)
// ---------------------------------------------------------------------------
template<int Cin, int CinReal, int IN, int Kout, int OUT, int BN>
__global__ void __launch_bounds__(256)
conv_mfma(const unsigned short* __restrict__ in, const unsigned short* __restrict__ wB,
          const float* __restrict__ bias, unsigned short* __restrict__ out)
{
  constexpr int SPB = OUT*OUT;
  constexpr int KD  = Cin*16;
  __shared__ __align__(16) unsigned short Alds[64*40];
  __shared__ __align__(16) unsigned short Blds[BN*40];

  const int tid  = threadIdx.x;
  const int wave = tid >> 6, lane = tid & 63;
  const unsigned m0 = blockIdx.x * 64;
  const int n0 = blockIdx.y * BN;

  const int ar  = tid >> 2;
  const int aq  = tid & 3;
  const int c2  = aq >> 1;
  const int kh0 = (aq & 1) * 2;
  const unsigned m   = m0 + ar;
  const unsigned nim = m / SPB;
  const unsigned sp  = m % SPB;
  const int oy = sp / OUT, ox = sp % OUT;
  const int ix0 = ox*2 - 1;
  const unsigned short* inN = in + (size_t)nim * CinReal * IN * IN;
  int  iyoff[2]; bool iyok[2];
#pragma unroll
  for (int dh = 0; dh < 2; dh++){
    int iy = oy*2 - 1 + kh0 + dh;
    iyok[dh]  = (iy >= 0 && iy < IN);
    iyoff[dh] = iyok[dh] ? iy*IN : 0;
  }
  bool ixok[4];
#pragma unroll
  for (int kw = 0; kw < 4; kw++) ixok[kw] = (ix0+kw >= 0 && ix0+kw < IN);
  unsigned short* Adst = &Alds[ar*40 + c2*16 + kh0*4];

  const int bn = tid >> 2;
  const int bi = tid & 3;
  const unsigned short* Bsrc = wB + (size_t)(n0 + bn)*KD + bi*8;
  unsigned short* Bdst = &Blds[bn*40 + bi*8];

  frag_cd acc[BN/16];
#pragma unroll
  for (int g = 0; g < BN/16; g++) acc[g] = (frag_cd){0.f,0.f,0.f,0.f};

  const int lrow = lane & 15;
  const int lk   = (lane >> 4) * 8;

#pragma unroll 1
  for (int kt = 0; kt < KD/32; kt++){
    {
      union { unsigned short s[8]; uint4 v; } va;
#pragma unroll
      for (int j = 0; j < 8; j++) va.s[j] = 0;
      const int c = kt*2 + c2;
      if (Cin == CinReal || c < CinReal){
        const unsigned short* ip = inN + (size_t)c * IN * IN;
#pragma unroll
        for (int dh = 0; dh < 2; dh++){
          if (iyok[dh]){
#pragma unroll
            for (int kw = 0; kw < 4; kw++)
              if (ixok[kw]) va.s[dh*4+kw] = ip[iyoff[dh] + ix0 + kw];
          }
        }
      }
      *(uint4*)Adst = va.v;
    }
    if (tid < BN*4)
      *(uint4*)Bdst = *(const uint4*)(Bsrc + kt*32);
    __syncthreads();

    frag_ab a = *(const frag_ab*)&Alds[(wave*16 + lrow)*40 + lk];
#pragma unroll
    for (int g = 0; g < BN/16; g++){
      frag_ab b = *(const frag_ab*)&Blds[(g*16 + lrow)*40 + lk];
      acc[g] = __builtin_amdgcn_mfma_f32_16x16x32_bf16(a, b, acc[g], 0, 0, 0);
    }
    __syncthreads();
  }

  const unsigned mbase = m0 + wave*16 + ((lane >> 4) << 2);
  const unsigned nim_o = mbase / SPB;
  const unsigned spo   = mbase % SPB;
#pragma unroll
  for (int g = 0; g < BN/16; g++){
    const int ko = n0 + g*16 + (lane & 15);
    const float bv = bias[ko];
    union { unsigned short s[4]; uint2 v; } u;
#pragma unroll
    for (int r = 0; r < 4; r++) u.s[r] = f2bf(fmaxf(acc[g][r] + bv, 0.f));
    *(uint2*)(out + ((size_t)nim_o*Kout + ko)*SPB + spo) = u.v;
  }
}

// ---------------------------------------------------------------------------
// FC GEMM (unchanged R2)
// ---------------------------------------------------------------------------
__global__ void __launch_bounds__(256)
fc_mfma(const unsigned short* __restrict__ A, const unsigned short* __restrict__ wB,
        const float* __restrict__ bias, float* __restrict__ outF)
{
  constexpr int KD = 4096, BN = 64, Kout = 256;
  __shared__ __align__(16) unsigned short Alds[64*40];
  __shared__ __align__(16) unsigned short Blds[BN*40];

  const int tid  = threadIdx.x;
  const int wave = tid >> 6, lane = tid & 63;
  const int m0 = blockIdx.x * 64;
  const int n0 = blockIdx.y * BN;

  const int ar = tid >> 2, ai = tid & 3;
  const unsigned short* Asrc = A + (size_t)(m0 + ar)*KD + ai*8;
  unsigned short* Adst = &Alds[ar*40 + ai*8];
  const int bn = tid >> 2, bi = tid & 3;
  const unsigned short* Bsrc = wB + (size_t)(n0 + bn)*KD + bi*8;
  unsigned short* Bdst = &Blds[bn*40 + bi*8];

  frag_cd acc[BN/16];
#pragma unroll
  for (int g = 0; g < BN/16; g++) acc[g] = (frag_cd){0.f,0.f,0.f,0.f};

  const int lrow = lane & 15;
  const int lk   = (lane >> 4) * 8;

#pragma unroll 1
  for (int kt = 0; kt < KD/32; kt++){
    *(uint4*)Adst = *(const uint4*)(Asrc + kt*32);
    *(uint4*)Bdst = *(const uint4*)(Bsrc + kt*32);
    __syncthreads();
    frag_ab a = *(const frag_ab*)&Alds[(wave*16 + lrow)*40 + lk];
#pragma unroll
    for (int g = 0; g < BN/16; g++){
      frag_ab b = *(const frag_ab*)&Blds[(g*16 + lrow)*40 + lk];
      acc[g] = __builtin_amdgcn_mfma_f32_16x16x32_bf16(a, b, acc[g], 0, 0, 0);
    }
    __syncthreads();
  }

  const int mbase = m0 + wave*16 + ((lane >> 4) << 2);
#pragma unroll
  for (int g = 0; g < BN/16; g++){
    const int ko = n0 + g*16 + (lane & 15);
    const float bv = bias[ko];
#pragma unroll
    for (int r = 0; r < 4; r++)
      outF[(size_t)(mbase + r)*Kout + ko] = acc[g][r] + bv;
  }
}

// ---------------------------------------------------------------------------
// RSSM scan v3: f16 dot2 + b128 LDS weight reads + 3 relaxed barriers/step.
// 384 threads: phase A all threads (one gate out each); phase B: thr 0..127
// prior (2/out), thr 128..383 posterior (4/out, interleaved mu/lv mapping so
// reparam happens in-wave via shfl_xor 4).
// ---------------------------------------------------------------------------
__global__ void __launch_bounds__(384)
rssm_scan3(const float* __restrict__ actions, const float* __restrict__ feats,
           const float* __restrict__ eps,
           const unsigned* __restrict__ g_scan,   // whh4 ++ po4
           const unsigned* __restrict__ g_wih2,   // [19][384]
           const unsigned* __restrict__ g_pr2,    // [64][64]
           const float* __restrict__ bih,  const float* __restrict__ bhh,
           const float* __restrict__ prior_b, const float* __restrict__ post_b,
           float* __restrict__ out)
{
  __shared__ __align__(16) unsigned lds_w[SCAN_U];
  __shared__ __align__(16) _Float16 sh_hfh[384];   // [0,128)=h, [128,384)=f
  __shared__ __align__(16) _Float16 sh_xh[40];     // [0,32)=z, [32,38)=a
  __shared__ __align__(16) float sh_gi[384];
  __shared__ __align__(16) float sh_gh[384];

  const int b = blockIdx.x, tid = threadIdx.x;

  // stage packed weights into LDS
  for (int i = tid; i < SCAN_U/4; i += 384)
    ((uint4*)lds_w)[i] = ((const uint4*)g_scan)[i];

  unsigned wih[19];
#pragma unroll
  for (int c = 0; c < 19; c++) wih[c] = g_wih2[c*384 + tid];

  unsigned prw[32];
  float prb = 0.f;
  if (tid < 128){
    const unsigned* src = g_pr2 + (tid >> 1)*64 + (tid & 1)*32;
#pragma unroll
    for (int c = 0; c < 32; c++) prw[c] = src[c];
    prb = prior_b[tid >> 1];
  }

  // posterior geometry
  int om = 0, pj = 0, o_p = 0; bool is_mu = false; float pob = 0.f;
  if (tid >= 128){
    const int tt = tid - 128;
    om = tt >> 2; pj = tt & 3;
    o_p = (om >> 1) + (om & 1)*32;
    is_mu = !(om & 1);
    pob = post_b[o_p];
  }

  const float bih_i = bih[tid], bhh_i = bhh[tid];
  float hreg = 0.f;

  // ---- preloop staging for t=0 ----
  {
    const int bt0 = b*Tn;
    if (tid < Hn) sh_hfh[tid] = (_Float16)0.f;
    if (tid < Ln) sh_xh[tid] = (_Float16)0.f;
    if (tid >= 32 && tid < 38) sh_xh[tid] = (_Float16)actions[(size_t)bt0*An + (tid-32)];
    if (tid >= 64 && tid < 320) sh_hfh[128 + tid - 64] = (_Float16)feats[(size_t)bt0*FDn + (tid-64)];
  }
  __syncthreads();

  const uint4* whh4 = (const uint4*)lds_w;            // [k8][384]
  const uint4* po4  = (const uint4*)(lds_w + WHH4_U); // [o][53], j*13+kk
  const uint4* H4   = (const uint4*)sh_hfh;
  const unsigned* X2 = (const unsigned*)sh_xh;

  const int OFF_MUP = 0;
  const int OFF_LVP = Bn*Tn*Ln;
  const int OFF_MUQ = 2*Bn*Tn*Ln;
  const int OFF_LVQ = 3*Bn*Tn*Ln;
  const int OFF_H   = 4*Bn*Tn*Ln;
  const int OFF_Z   = 4*Bn*Tn*Ln + Bn*Tn*Hn;

  float freg = 0.f, areg = 0.f, epsr = 0.f;

  for (int t = 0; t < Tn; t++){
    const int bt = b*Tn + t;

    // ---- A-segment ----
    // write f_t staged last iter (t>0); prefetch t+1 inputs; eps_t
    if (t > 0 && tid >= 64 && tid < 320) sh_hfh[128 + tid - 64] = (_Float16)freg;
    if (t < Tn-1){
      if (tid >= 64 && tid < 320) freg = feats[(size_t)(bt+1)*FDn + (tid-64)];
      if (tid >= 320 && tid < 326) areg = actions[(size_t)(bt+1)*An + (tid-320)];
    }
    if (tid >= 128 && ((tid-128)&7) == 0) epsr = eps[(size_t)bt*Ln + ((tid-128)>>3)];

    // gates
    {
      float a0 = bih_i, a1 = 0.f;
#pragma unroll
      for (int c = 0; c < 19; c += 2) a0 = fdot2u(wih[c], X2[c], a0);
#pragma unroll
      for (int c = 1; c < 19; c += 2) a1 = fdot2u(wih[c], X2[c], a1);
      sh_gi[tid] = a0 + a1;

      float g0 = bhh_i, g1 = 0.f, g2 = 0.f, g3 = 0.f;
      const uint4* Wp = whh4 + tid;
#pragma unroll
      for (int k8 = 0; k8 < 16; k8++){
        uint4 w = Wp[k8*384];
        uint4 h = H4[k8];
        g0 = fdot2u(w.x, h.x, g0);
        g1 = fdot2u(w.y, h.y, g1);
        g2 = fdot2u(w.z, h.z, g2);
        g3 = fdot2u(w.w, h.w, g3);
      }
      sh_gh[tid] = (g0 + g1) + (g2 + g3);
    }
    BAR_LDS();   // B2

    // ---- C-segment: GRU combine (thr<128); a_{t+1} stage (thr 320..325) ----
    if (tid < Hn){
      const float r  = sigmoidf(sh_gi[tid]       + sh_gh[tid]);
      const float zg = sigmoidf(sh_gi[Hn  + tid] + sh_gh[Hn  + tid]);
      const float nn = tanhf(fmaf(r, sh_gh[2*Hn + tid], sh_gi[2*Hn + tid]));
      hreg = (1.f - zg)*nn + zg*hreg;
      sh_hfh[tid] = (_Float16)hreg;
      out[OFF_H + (size_t)bt*Hn + tid] = hreg;
    }
    if (t < Tn-1 && tid >= 320 && tid < 326) sh_xh[32 + tid - 320] = (_Float16)areg;
    BAR_LDS();   // B3

    // ---- B-segment: prior / posterior (+reparam in-wave) ----
    if (tid < 128){
      const int j = tid & 1;
      float a0 = 0.f, a1 = 0.f, a2 = 0.f, a3 = 0.f;
#pragma unroll
      for (int c4 = 0; c4 < 8; c4++){
        uint4 h = H4[8*j + c4];
        a0 = fdot2u(prw[4*c4+0], h.x, a0);
        a1 = fdot2u(prw[4*c4+1], h.y, a1);
        a2 = fdot2u(prw[4*c4+2], h.z, a2);
        a3 = fdot2u(prw[4*c4+3], h.w, a3);
      }
      float p = (a0 + a1) + (a2 + a3);
      p += __shfl_xor(p, 1);
      if (j == 0){
        const int o = tid >> 1;
        p += prb;
        if (o < Ln) out[OFF_MUP + (size_t)bt*Ln + o] = p;
        else        out[OFF_LVP + (size_t)bt*Ln + (o - Ln)] = p;
      }
    } else {
      const uint4* W = po4 + o_p*53 + pj*13;
      float a0 = 0.f, a1 = 0.f, a2 = 0.f, a3 = 0.f;
#pragma unroll
      for (int kk = 0; kk < 12; kk++){
        uint4 w = W[kk];
        uint4 h = H4[pj*12 + kk];
        a0 = fdot2u(w.x, h.x, a0);
        a1 = fdot2u(w.y, h.y, a1);
        a2 = fdot2u(w.z, h.z, a2);
        a3 = fdot2u(w.w, h.w, a3);
      }
      float p = (a0 + a1) + (a2 + a3);
      p += __shfl_xor(p, 1);
      p += __shfl_xor(p, 2);     // now all 4 j-lanes hold the sum
      p += pob;                  // biased q for this om
      const float q_part = __shfl_xor(p, 4);  // partner om^1 (mu<->lv)
      if (pj == 0){
        if (is_mu){
          const int o = om >> 1;
          out[OFF_MUQ + (size_t)bt*Ln + o] = p;
          const float zz = fmaf(expf(0.5f*q_part), epsr, p);
          sh_xh[o] = (_Float16)zz;
          out[OFF_Z + (size_t)bt*Ln + o] = zz;
        } else {
          out[OFF_LVQ + (size_t)bt*Ln + (o_p - Ln)] = p;
        }
      }
    }
    BAR_LDS();   // B4: z/a/f visible for next phase A
  }
}

// ---------------------------------------------------------------------------
extern "C" void kernel_launch(void* const* d_in, const int* in_sizes, int n_in,
                              void* d_out, int out_size, void* d_ws, size_t ws_size,
                              hipStream_t stream)
{
  const float* states = (const float*)d_in[0];
  const float* actions= (const float*)d_in[1];
  const float* c1_w = (const float*)d_in[2];  const float* c1_b = (const float*)d_in[3];
  const float* c2_w = (const float*)d_in[4];  const float* c2_b = (const float*)d_in[5];
  const float* c3_w = (const float*)d_in[6];  const float* c3_b = (const float*)d_in[7];
  const float* c4_w = (const float*)d_in[8];  const float* c4_b = (const float*)d_in[9];
  const float* fc_w = (const float*)d_in[10]; const float* fc_b = (const float*)d_in[11];
  const float* gwih = (const float*)d_in[12]; const float* gwhh = (const float*)d_in[13];
  const float* gbih = (const float*)d_in[14]; const float* gbhh = (const float*)d_in[15];
  const float* pr_w = (const float*)d_in[16]; const float* pr_b = (const float*)d_in[17];
  const float* po_w = (const float*)d_in[18]; const float* po_b = (const float*)d_in[19];
  const float* eps  = (const float*)d_in[20];

  char* p = (char*)d_ws;
  auto alloc = [&](size_t bytes){ char* r = p; p += (bytes + 255) & ~255ULL; return r; };

  unsigned short* statesB = (unsigned short*)alloc((size_t)Nimg*3*64*64*2);
  unsigned short* act1    = (unsigned short*)alloc((size_t)Nimg*32*1024*2);
  unsigned short* act2    = (unsigned short*)alloc((size_t)Nimg*64*256*2);
  unsigned short* act3    = (unsigned short*)alloc((size_t)Nimg*128*64*2);
  unsigned short* act4    = (unsigned short*)alloc((size_t)Nimg*256*16*2);
  float*          feats   = (float*)alloc((size_t)Nimg*FDn*4);
  unsigned short* w1b     = (unsigned short*)alloc(32*64*2);
  unsigned short* w2b     = (unsigned short*)alloc(64*512*2);
  unsigned short* w3b     = (unsigned short*)alloc((size_t)128*1024*2);
  unsigned short* w4b     = (unsigned short*)alloc((size_t)256*2048*2);
  unsigned short* wfcb    = (unsigned short*)alloc((size_t)256*4096*2);
  unsigned* g_scan = (unsigned*)alloc((size_t)SCAN_U*4);
  unsigned* g_wih2 = (unsigned*)alloc((size_t)19*384*4);
  unsigned* g_pr2  = (unsigned*)alloc((size_t)64*64*4);

  // states -> bf16
  {
    int n = Nimg*3*64*64;
    f2bf_kernel<<<(n/4+255)/256, 256, 0, stream>>>(states, statesB, n);
  }
  // all weight conversions + scan packs in one kernel
  prep_kernel<<<1893, 256, 0, stream>>>(c2_w, c3_w, c4_w, fc_w, c1_w,
                                        gwhh, gwih, pr_w, po_w,
                                        w2b, w3b, w4b, wfcb, w1b,
                                        g_scan, g_wih2, g_pr2);

  // encoder: implicit-GEMM MFMA convs
  conv_mfma<4,3,64,32,32,32>   <<< dim3(Nimg*1024/64, 1), 256, 0, stream >>>(statesB, w1b, c1_b, act1);
  conv_mfma<32,32,32,64,16,64> <<< dim3(Nimg*256/64, 1), 256, 0, stream >>>(act1, w2b, c2_b, act2);
  conv_mfma<64,64,16,128,8,64> <<< dim3(Nimg*64/64, 2), 256, 0, stream >>>(act2, w3b, c3_b, act3);
  conv_mfma<128,128,8,256,4,64><<< dim3(Nimg*16/64, 4), 256, 0, stream >>>(act3, w4b, c4_b, act4);

  fc_mfma<<< dim3(Nimg/64, 4), 256, 0, stream >>>(act4, wfcb, fc_b, feats);

  rssm_scan3<<< Bn, 384, 0, stream >>>(actions, feats, eps,
                                       g_scan, g_wih2, g_pr2,
                                       gbih, gbhh, pr_b, po_b, (float*)d_out);
}

// Round 5
// 704.190 us; speedup vs baseline: 25.9560x; 1.2041x over previous
//
#include <hip/hip_runtime.h>
#include <math.h>

#define Bn 32
#define Tn 64
#define An 6
#define Ln 32
#define Hn 128
#define FDn 256
#define Nimg (Bn*Tn)   // 2048

typedef __attribute__((ext_vector_type(8))) short frag_ab;   // 8 bf16
typedef __attribute__((ext_vector_type(4))) float frag_cd;   // 4 fp32
typedef _Float16 h2_t __attribute__((ext_vector_type(2)));

__device__ __forceinline__ float sigmoidf(float x){ return 1.f/(1.f + expf(-x)); }

__device__ __forceinline__ unsigned short f2bf(float f){
  unsigned int u = __float_as_uint(f);
  unsigned int r = (u + 0x7fffu + ((u >> 16) & 1u)) >> 16;
  return (unsigned short)r;
}
__device__ __forceinline__ unsigned packh(float a, float b){
  union { h2_t h; unsigned u; } x;
  x.h = (h2_t){(_Float16)a, (_Float16)b};
  return x.u;
}
__device__ __forceinline__ float fdot2u(unsigned a, unsigned b, float c){
  union { unsigned u; h2_t h; } ua, ub;
  ua.u = a; ub.u = b;
#if __has_builtin(__builtin_amdgcn_fdot2)
  return __builtin_amdgcn_fdot2(ua.h, ub.h, c, false);
#else
  return c + (float)ua.h.x*(float)ub.h.x + (float)ua.h.y*(float)ub.h.y;
#endif
}
// barrier without vmcnt drain: global stores in-flight are never read in-kernel
#define BAR_LDS() asm volatile("s_waitcnt lgkmcnt(0)\n\ts_barrier" ::: "memory")

// ---------------------------------------------------------------------------
// states: (2048, 3, 64, 64) fp32 NCHW -> (2048, 64, 64, 4) bf16 NHWC (c3 = 0)
// ---------------------------------------------------------------------------
__global__ void __launch_bounds__(256)
states_nhwc_kernel(const float* __restrict__ src, unsigned short* __restrict__ dst)
{
  int idx = blockIdx.x*256 + threadIdx.x;      // 2048*4096
  int n = idx >> 12, pix = idx & 4095;
  const float* s = src + (size_t)n*3*4096 + pix;
  union { unsigned short e[4]; uint2 v; } u;
  u.e[0] = f2bf(s[0]); u.e[1] = f2bf(s[4096]); u.e[2] = f2bf(s[8192]); u.e[3] = 0;
  *(uint2*)(dst + (size_t)idx*4) = u.v;
}

// ---------------------------------------------------------------------------
// Scan weight image layout (f16 pairs, uints):
#define WHH4_U 24576
#define PO4_U  (64*53*4)        // 13568
#define SCAN_U (WHH4_U + PO4_U) // 38144 uints = 152576 B

// merged prep: conv/fc weight permute->bf16 (tap-major, c-fast) + scan f16 packs
__global__ void __launch_bounds__(256)
prep2_kernel(const float* __restrict__ c1w, const float* __restrict__ c2w,
             const float* __restrict__ c3w, const float* __restrict__ c4w,
             const float* __restrict__ fcw,
             const float* __restrict__ gwhh, const float* __restrict__ gwih,
             const float* __restrict__ prw,  const float* __restrict__ pow_,
             unsigned short* __restrict__ w1p, unsigned short* __restrict__ w2p,
             unsigned short* __restrict__ w3p, unsigned short* __restrict__ w4p,
             unsigned short* __restrict__ wfcp,
             unsigned* __restrict__ g_scan, unsigned* __restrict__ g_wih2,
             unsigned* __restrict__ g_pr2)
{
  const int bid = blockIdx.x, tid = threadIdx.x;
  if (bid < 128){            // c2: (64,32,16) -> [k][tap*32+c]
    int idx = bid*256+tid;
    int k = idx >> 9, r = idx & 511, tap = r >> 5, c = r & 31;
    w2p[idx] = f2bf(c2w[k*512 + c*16 + tap]);
  } else if (bid < 640){     // c3: (128,64,16)
    int idx = (bid-128)*256+tid;
    int k = idx >> 10, r = idx & 1023, tap = r >> 6, c = r & 63;
    w3p[idx] = f2bf(c3w[k*1024 + c*16 + tap]);
  } else if (bid < 2688){    // c4: (256,128,16)
    int idx = (bid-640)*256+tid;
    int k = idx >> 11, r = idx & 2047, tap = r >> 7, c = r & 127;
    w4p[idx] = f2bf(c4w[k*2048 + c*16 + tap]);
  } else if (bid < 6784){    // fc: [o][sp*256+c] = src[o*4096 + c*16 + sp]
    int idx = (bid-2688)*256+tid;
    int o = idx >> 12, r = idx & 4095, sp = r >> 8, c = r & 255;
    wfcp[idx] = f2bf(fcw[o*4096 + c*16 + sp]);
  } else if (bid < 6792){    // c1: (32,3,16) -> [k][tap*4+c], c3=0
    int idx = (bid-6784)*256+tid;
    int k = idx >> 6, r = idx & 63, tap = r >> 2, c = r & 3;
    w1p[idx] = (c < 3) ? f2bf(c1w[k*48 + c*16 + tap]) : (unsigned short)0;
  } else if (bid < 6888){    // whh pack: 24576 uints
    int idx = (bid-6792)*256+tid;
    int q = idx & 3, r2 = idx >> 2;
    int k8 = r2 / 384, i = r2 - k8*384;
    int k = 8*k8 + 2*q;
    g_scan[idx] = packh(gwhh[i*128 + k], gwhh[i*128 + k + 1]);
  } else if (bid < 6917){    // wih pack: 7296 uints
    int idx = (bid-6888)*256+tid;
    if (idx < 19*384){
      int c = idx / 384, i = idx - c*384;
      g_wih2[idx] = packh(gwih[i*38 + 2*c], gwih[i*38 + 2*c + 1]);
    }
  } else if (bid < 6933){    // prior pack: 4096 uints
    int idx = (bid-6917)*256+tid;
    int o = idx >> 6, c = idx & 63;
    g_pr2[idx] = packh(prw[o*128 + 2*c], prw[o*128 + 2*c + 1]);
  } else {                   // post pack: 12288 entries
    int idx = (bid-6933)*256+tid;
    if (idx < 64*192){
      int o = idx / 192, r2 = idx - o*192;
      int u = r2 >> 2, q = r2 & 3;
      int j = u / 12, kk = u - j*12;
      int k = 96*j + 8*kk + 2*q;
      g_scan[WHH4_U + (o*53 + j*13 + kk)*4 + q] =
        packh(pow_[o*384 + k], pow_[o*384 + k + 1]);
    }
  }
}

// ---------------------------------------------------------------------------
// NHWC implicit-GEMM conv (k=4, s=2, p=1), MFMA 16x16x32 bf16.
// BM=128 x BN, 4 waves (2x2), BK=32. LDS is FRAGMENT-MAJOR: element (row m,
// k) of frag f lives at f*512 + (m&15)*8 + (k>>3)*128 + (k&7) -> every
// ds_read_b128 is base + lane*16B (conflict-free); staging writes are 2-way
// max (free). Register prefetch of chunk kt+1 overlaps MFMA of kt.
// ---------------------------------------------------------------------------
template<int Cin, int IN, int Kout, int OUT, int BN, int LOG_SPB>
__global__ void __launch_bounds__(256)
convN_mfma(const unsigned short* __restrict__ in,   // NHWC (n, IN, IN, Cin)
           const unsigned short* __restrict__ wB,   // (Kout, 16*Cin) tap-major
           const float* __restrict__ bias,
           unsigned short* __restrict__ out)        // NHWC (n, OUT, OUT, Kout)
{
  constexpr int SPB = OUT*OUT;
  constexpr int KD  = 16*Cin;
  constexpr int NCH = KD/32;
  constexpr int NFN = BN/32;          // n-frags per wave
  __shared__ __align__(16) unsigned short Alds[8*512];
  __shared__ __align__(16) unsigned short Blds[(BN/16)*512];

  const int tid = threadIdx.x;
  const int wave = tid >> 6, lane = tid & 63;
  const unsigned m0 = blockIdx.x * 128;
  const int n0 = blockIdx.y * BN;

  // A staging geometry: thread covers (row r=tid>>2, piece p=tid&3) and (r+64, p)
  const int p = tid & 3;
  const unsigned short* baseA[2]; int oyA[2], oxA[2]; unsigned short* Adst[2];
#pragma unroll
  for (int h = 0; h < 2; h++){
    int r = (tid >> 2) + h*64;
    unsigned m = m0 + r;
    int nimg = m >> LOG_SPB;
    int sp = m & (SPB - 1);
    oyA[h] = sp / OUT; oxA[h] = sp & (OUT - 1);
    baseA[h] = in + (size_t)nimg * IN * IN * Cin;
    Adst[h] = &Alds[((r >> 4) << 9) + ((r & 15) << 3) + (p << 7)];
  }

  // B staging: thread t < BN*4 covers (n=t>>2, piece pb=t&3)
  const int bn = tid >> 2, pb = tid & 3;
  const bool bAct = tid < BN*4;
  const unsigned short* Bsrc0 = wB + (size_t)(n0 + bn)*KD + pb*8;
  unsigned short* Bdst = &Blds[((bn >> 4) << 9) + ((bn & 15) << 3) + (pb << 7)];

  const int mhalf = wave >> 1, nhalf = wave & 1;
  frag_cd acc[4][NFN];
#pragma unroll
  for (int i = 0; i < 4; i++)
#pragma unroll
    for (int j = 0; j < NFN; j++) acc[i][j] = (frag_cd){0.f,0.f,0.f,0.f};

  auto loadA = [&](int kt, int h) -> uint4 {
    if constexpr (Cin >= 32){
      constexpr int CPT = Cin/32;
      int tap = kt / CPT;
      int c0 = (kt - tap*CPT)*32;
      int kh = tap >> 2, kw = tap & 3;
      int iy = 2*oyA[h] - 1 + kh;
      int ix = 2*oxA[h] - 1 + kw;
      uint4 v = {0u,0u,0u,0u};
      if ((unsigned)iy < (unsigned)IN && (unsigned)ix < (unsigned)IN)
        v = *(const uint4*)(baseA[h] + ((iy*IN + ix)*Cin + c0 + p*8));
      return v;
    } else {
      // Cin==4 (conv1): chunk kt covers kh = kt*2 + (p>>1); piece = 2 kw x 4 c
      int kh = kt*2 + (p >> 1);
      int kw0 = (p & 1)*2;
      int iy = 2*oyA[h] - 1 + kh;
      int ix0 = 2*oxA[h] - 1 + kw0;
      union { uint2 u2[2]; uint4 u4; } v; v.u4 = (uint4){0u,0u,0u,0u};
      bool iyok = (unsigned)iy < (unsigned)IN;
      const unsigned short* rowp = baseA[h] + iy*IN*4;
#pragma unroll
      for (int d = 0; d < 2; d++){
        int ix = ix0 + d;
        if (iyok && (unsigned)ix < (unsigned)IN) v.u2[d] = *(const uint2*)(rowp + ix*4);
      }
      return v.u4;
    }
  };

  uint4 aPre0 = loadA(0,0), aPre1 = loadA(0,1);
  uint4 bPre = bAct ? *(const uint4*)Bsrc0 : (uint4){0u,0u,0u,0u};

#pragma unroll 1
  for (int kt = 0; kt < NCH; kt++){
    *(uint4*)Adst[0] = aPre0;
    *(uint4*)Adst[1] = aPre1;
    if (bAct) *(uint4*)Bdst = bPre;
    __syncthreads();
    if (kt + 1 < NCH){
      aPre0 = loadA(kt+1, 0);
      aPre1 = loadA(kt+1, 1);
      if (bAct) bPre = *(const uint4*)(Bsrc0 + (kt+1)*32);
    }
    frag_ab a[4], bf[NFN];
#pragma unroll
    for (int i = 0; i < 4; i++)
      a[i] = *(const frag_ab*)&Alds[(((mhalf<<2) + i) << 9) + lane*8];
#pragma unroll
    for (int j = 0; j < NFN; j++)
      bf[j] = *(const frag_ab*)&Blds[((nhalf*NFN + j) << 9) + lane*8];
#pragma unroll
    for (int i = 0; i < 4; i++)
#pragma unroll
      for (int j = 0; j < NFN; j++)
        acc[i][j] = __builtin_amdgcn_mfma_f32_16x16x32_bf16(a[i], bf[j], acc[i][j], 0, 0, 0);
    __syncthreads();
  }

  // epilogue: NHWC out index = m*Kout + k (no div/mod)
  const unsigned mb = m0 + mhalf*64 + ((lane >> 4) << 2);
#pragma unroll
  for (int j = 0; j < NFN; j++){
    const int kg = n0 + nhalf*(NFN*16) + j*16 + (lane & 15);
    const float bv = bias[kg];
#pragma unroll
    for (int i = 0; i < 4; i++){
#pragma unroll
      for (int r = 0; r < 4; r++){
        unsigned mg = mb + i*16 + r;
        out[(size_t)mg*Kout + kg] = f2bf(fmaxf(acc[i][j][r] + bv, 0.f));
      }
    }
  }
}

// ---------------------------------------------------------------------------
// FC GEMM: A (2048 x 4096) bf16 (NHWC-flat act4), W (256 x 4096) permuted.
// BM=64 x BN=64, 2x2 waves, fragment-major LDS, out fp32 feats.
// ---------------------------------------------------------------------------
__global__ void __launch_bounds__(256)
fc_mfma2(const unsigned short* __restrict__ A, const unsigned short* __restrict__ wB,
         const float* __restrict__ bias, float* __restrict__ outF)
{
  constexpr int KD = 4096, NCH = KD/32;
  __shared__ __align__(16) unsigned short Alds[4*512];
  __shared__ __align__(16) unsigned short Blds[4*512];

  const int tid = threadIdx.x, wave = tid >> 6, lane = tid & 63;
  const int m0 = blockIdx.x * 64, n0 = blockIdx.y * 64;
  const int r = tid >> 2, pc = tid & 3;
  const unsigned short* Asrc = A + (size_t)(m0 + r)*KD + pc*8;
  const unsigned short* Bsrc = wB + (size_t)(n0 + r)*KD + pc*8;
  unsigned short* Adst = &Alds[((r >> 4) << 9) + ((r & 15) << 3) + (pc << 7)];
  unsigned short* Bdst = &Blds[((r >> 4) << 9) + ((r & 15) << 3) + (pc << 7)];
  const int mh = wave >> 1, nh = wave & 1;

  frag_cd acc[2][2];
#pragma unroll
  for (int i = 0; i < 2; i++)
#pragma unroll
    for (int j = 0; j < 2; j++) acc[i][j] = (frag_cd){0.f,0.f,0.f,0.f};

  uint4 aP = *(const uint4*)Asrc, bP = *(const uint4*)Bsrc;
#pragma unroll 1
  for (int kt = 0; kt < NCH; kt++){
    *(uint4*)Adst = aP;
    *(uint4*)Bdst = bP;
    __syncthreads();
    if (kt + 1 < NCH){
      aP = *(const uint4*)(Asrc + (kt+1)*32);
      bP = *(const uint4*)(Bsrc + (kt+1)*32);
    }
    frag_ab a[2], b[2];
#pragma unroll
    for (int i = 0; i < 2; i++) a[i] = *(const frag_ab*)&Alds[(((mh<<1)+i) << 9) + lane*8];
#pragma unroll
    for (int j = 0; j < 2; j++) b[j] = *(const frag_ab*)&Blds[(((nh<<1)+j) << 9) + lane*8];
#pragma unroll
    for (int i = 0; i < 2; i++)
#pragma unroll
      for (int j = 0; j < 2; j++)
        acc[i][j] = __builtin_amdgcn_mfma_f32_16x16x32_bf16(a[i], b[j], acc[i][j], 0, 0, 0);
    __syncthreads();
  }

  const int mb = m0 + mh*32 + ((lane >> 4) << 2);
#pragma unroll
  for (int j = 0; j < 2; j++){
    const int kg = n0 + nh*32 + j*16 + (lane & 15);
    const float bv = bias[kg];
#pragma unroll
    for (int i = 0; i < 2; i++)
#pragma unroll
      for (int rr = 0; rr < 4; rr++)
        outF[(size_t)(mb + i*16 + rr)*256 + kg] = acc[i][j][rr] + bv;
  }
}

// ---------------------------------------------------------------------------
// RSSM scan v3 (unchanged from R3)
// ---------------------------------------------------------------------------
__global__ void __launch_bounds__(384)
rssm_scan3(const float* __restrict__ actions, const float* __restrict__ feats,
           const float* __restrict__ eps,
           const unsigned* __restrict__ g_scan,
           const unsigned* __restrict__ g_wih2,
           const unsigned* __restrict__ g_pr2,
           const float* __restrict__ bih,  const float* __restrict__ bhh,
           const float* __restrict__ prior_b, const float* __restrict__ post_b,
           float* __restrict__ out)
{
  __shared__ __align__(16) unsigned lds_w[SCAN_U];
  __shared__ __align__(16) _Float16 sh_hfh[384];
  __shared__ __align__(16) _Float16 sh_xh[40];
  __shared__ __align__(16) float sh_gi[384];
  __shared__ __align__(16) float sh_gh[384];

  const int b = blockIdx.x, tid = threadIdx.x;

  for (int i = tid; i < SCAN_U/4; i += 384)
    ((uint4*)lds_w)[i] = ((const uint4*)g_scan)[i];

  unsigned wih[19];
#pragma unroll
  for (int c = 0; c < 19; c++) wih[c] = g_wih2[c*384 + tid];

  unsigned prw[32];
  float prb = 0.f;
  if (tid < 128){
    const unsigned* src = g_pr2 + (tid >> 1)*64 + (tid & 1)*32;
#pragma unroll
    for (int c = 0; c < 32; c++) prw[c] = src[c];
    prb = prior_b[tid >> 1];
  }

  int om = 0, pj = 0, o_p = 0; bool is_mu = false; float pob = 0.f;
  if (tid >= 128){
    const int tt = tid - 128;
    om = tt >> 2; pj = tt & 3;
    o_p = (om >> 1) + (om & 1)*32;
    is_mu = !(om & 1);
    pob = post_b[o_p];
  }

  const float bih_i = bih[tid], bhh_i = bhh[tid];
  float hreg = 0.f;

  {
    const int bt0 = b*Tn;
    if (tid < Hn) sh_hfh[tid] = (_Float16)0.f;
    if (tid < Ln) sh_xh[tid] = (_Float16)0.f;
    if (tid >= 32 && tid < 38) sh_xh[tid] = (_Float16)actions[(size_t)bt0*An + (tid-32)];
    if (tid >= 64 && tid < 320) sh_hfh[128 + tid - 64] = (_Float16)feats[(size_t)bt0*FDn + (tid-64)];
  }
  __syncthreads();

  const uint4* whh4 = (const uint4*)lds_w;
  const uint4* po4  = (const uint4*)(lds_w + WHH4_U);
  const uint4* H4   = (const uint4*)sh_hfh;
  const unsigned* X2 = (const unsigned*)sh_xh;

  const int OFF_MUP = 0;
  const int OFF_LVP = Bn*Tn*Ln;
  const int OFF_MUQ = 2*Bn*Tn*Ln;
  const int OFF_LVQ = 3*Bn*Tn*Ln;
  const int OFF_H   = 4*Bn*Tn*Ln;
  const int OFF_Z   = 4*Bn*Tn*Ln + Bn*Tn*Hn;

  float freg = 0.f, areg = 0.f, epsr = 0.f;

  for (int t = 0; t < Tn; t++){
    const int bt = b*Tn + t;

    if (t > 0 && tid >= 64 && tid < 320) sh_hfh[128 + tid - 64] = (_Float16)freg;
    if (t < Tn-1){
      if (tid >= 64 && tid < 320) freg = feats[(size_t)(bt+1)*FDn + (tid-64)];
      if (tid >= 320 && tid < 326) areg = actions[(size_t)(bt+1)*An + (tid-320)];
    }
    if (tid >= 128 && ((tid-128)&7) == 0) epsr = eps[(size_t)bt*Ln + ((tid-128)>>3)];

    {
      float a0 = bih_i, a1 = 0.f;
#pragma unroll
      for (int c = 0; c < 19; c += 2) a0 = fdot2u(wih[c], X2[c], a0);
#pragma unroll
      for (int c = 1; c < 19; c += 2) a1 = fdot2u(wih[c], X2[c], a1);
      sh_gi[tid] = a0 + a1;

      float g0 = bhh_i, g1 = 0.f, g2 = 0.f, g3 = 0.f;
      const uint4* Wp = whh4 + tid;
#pragma unroll
      for (int k8 = 0; k8 < 16; k8++){
        uint4 w = Wp[k8*384];
        uint4 h = H4[k8];
        g0 = fdot2u(w.x, h.x, g0);
        g1 = fdot2u(w.y, h.y, g1);
        g2 = fdot2u(w.z, h.z, g2);
        g3 = fdot2u(w.w, h.w, g3);
      }
      sh_gh[tid] = (g0 + g1) + (g2 + g3);
    }
    BAR_LDS();

    if (tid < Hn){
      const float r  = sigmoidf(sh_gi[tid]       + sh_gh[tid]);
      const float zg = sigmoidf(sh_gi[Hn  + tid] + sh_gh[Hn  + tid]);
      const float nn = tanhf(fmaf(r, sh_gh[2*Hn + tid], sh_gi[2*Hn + tid]));
      hreg = (1.f - zg)*nn + zg*hreg;
      sh_hfh[tid] = (_Float16)hreg;
      out[OFF_H + (size_t)bt*Hn + tid] = hreg;
    }
    if (t < Tn-1 && tid >= 320 && tid < 326) sh_xh[32 + tid - 320] = (_Float16)areg;
    BAR_LDS();

    if (tid < 128){
      const int j = tid & 1;
      float a0 = 0.f, a1 = 0.f, a2 = 0.f, a3 = 0.f;
#pragma unroll
      for (int c4 = 0; c4 < 8; c4++){
        uint4 h = H4[8*j + c4];
        a0 = fdot2u(prw[4*c4+0], h.x, a0);
        a1 = fdot2u(prw[4*c4+1], h.y, a1);
        a2 = fdot2u(prw[4*c4+2], h.z, a2);
        a3 = fdot2u(prw[4*c4+3], h.w, a3);
      }
      float p = (a0 + a1) + (a2 + a3);
      p += __shfl_xor(p, 1);
      if (j == 0){
        const int o = tid >> 1;
        p += prb;
        if (o < Ln) out[OFF_MUP + (size_t)bt*Ln + o] = p;
        else        out[OFF_LVP + (size_t)bt*Ln + (o - Ln)] = p;
      }
    } else {
      const uint4* W = po4 + o_p*53 + pj*13;
      float a0 = 0.f, a1 = 0.f, a2 = 0.f, a3 = 0.f;
#pragma unroll
      for (int kk = 0; kk < 12; kk++){
        uint4 w = W[kk];
        uint4 h = H4[pj*12 + kk];
        a0 = fdot2u(w.x, h.x, a0);
        a1 = fdot2u(w.y, h.y, a1);
        a2 = fdot2u(w.z, h.z, a2);
        a3 = fdot2u(w.w, h.w, a3);
      }
      float p = (a0 + a1) + (a2 + a3);
      p += __shfl_xor(p, 1);
      p += __shfl_xor(p, 2);
      p += pob;
      const float q_part = __shfl_xor(p, 4);
      if (pj == 0){
        if (is_mu){
          const int o = om >> 1;
          out[OFF_MUQ + (size_t)bt*Ln + o] = p;
          const float zz = fmaf(expf(0.5f*q_part), epsr, p);
          sh_xh[o] = (_Float16)zz;
          out[OFF_Z + (size_t)bt*Ln + o] = zz;
        } else {
          out[OFF_LVQ + (size_t)bt*Ln + (o_p - Ln)] = p;
        }
      }
    }
    BAR_LDS();
  }
}

// ---------------------------------------------------------------------------
extern "C" void kernel_launch(void* const* d_in, const int* in_sizes, int n_in,
                              void* d_out, int out_size, void* d_ws, size_t ws_size,
                              hipStream_t stream)
{
  const float* states = (const float*)d_in[0];
  const float* actions= (const float*)d_in[1];
  const float* c1_w = (const float*)d_in[2];  const float* c1_b = (const float*)d_in[3];
  const float* c2_w = (const float*)d_in[4];  const float* c2_b = (const float*)d_in[5];
  const float* c3_w = (const float*)d_in[6];  const float* c3_b = (const float*)d_in[7];
  const float* c4_w = (const float*)d_in[8];  const float* c4_b = (const float*)d_in[9];
  const float* fc_w = (const float*)d_in[10]; const float* fc_b = (const float*)d_in[11];
  const float* gwih = (const float*)d_in[12]; const float* gwhh = (const float*)d_in[13];
  const float* gbih = (const float*)d_in[14]; const float* gbhh = (const float*)d_in[15];
  const float* pr_w = (const float*)d_in[16]; const float* pr_b = (const float*)d_in[17];
  const float* po_w = (const float*)d_in[18]; const float* po_b = (const float*)d_in[19];
  const float* eps  = (const float*)d_in[20];

  char* p = (char*)d_ws;
  auto alloc = [&](size_t bytes){ char* r = p; p += (bytes + 255) & ~255ULL; return r; };

  unsigned short* statesB = (unsigned short*)alloc((size_t)Nimg*4096*4*2); // NHWC c=4
  unsigned short* act1    = (unsigned short*)alloc((size_t)Nimg*1024*32*2);
  unsigned short* act2    = (unsigned short*)alloc((size_t)Nimg*256*64*2);
  unsigned short* act3    = (unsigned short*)alloc((size_t)Nimg*64*128*2);
  unsigned short* act4    = (unsigned short*)alloc((size_t)Nimg*16*256*2);
  float*          feats   = (float*)alloc((size_t)Nimg*FDn*4);
  unsigned short* w1p     = (unsigned short*)alloc(32*64*2);
  unsigned short* w2p     = (unsigned short*)alloc((size_t)64*512*2);
  unsigned short* w3p     = (unsigned short*)alloc((size_t)128*1024*2);
  unsigned short* w4p     = (unsigned short*)alloc((size_t)256*2048*2);
  unsigned short* wfcp    = (unsigned short*)alloc((size_t)256*4096*2);
  unsigned* g_scan = (unsigned*)alloc((size_t)SCAN_U*4);
  unsigned* g_wih2 = (unsigned*)alloc((size_t)19*384*4);
  unsigned* g_pr2  = (unsigned*)alloc((size_t)64*64*4);

  states_nhwc_kernel<<<Nimg*4096/256, 256, 0, stream>>>(states, statesB);
  prep2_kernel<<<6981, 256, 0, stream>>>(c1_w, c2_w, c3_w, c4_w, fc_w,
                                         gwhh, gwih, pr_w, po_w,
                                         w1p, w2p, w3p, w4p, wfcp,
                                         g_scan, g_wih2, g_pr2);

  // encoder: NHWC implicit-GEMM MFMA convs (BM=128)
  convN_mfma<4,64,32,32,32,10>  <<< dim3(Nimg*1024/128, 1), 256, 0, stream >>>(statesB, w1p, c1_b, act1);
  convN_mfma<32,32,64,16,64,8>  <<< dim3(Nimg*256/128, 1), 256, 0, stream >>>(act1, w2p, c2_b, act2);
  convN_mfma<64,16,128,8,64,6>  <<< dim3(Nimg*64/128, 2), 256, 0, stream >>>(act2, w3p, c3_b, act3);
  convN_mfma<128,8,256,4,64,4>  <<< dim3(Nimg*16/128, 4), 256, 0, stream >>>(act3, w4p, c4_b, act4);

  fc_mfma2<<< dim3(Nimg/64, 4), 256, 0, stream >>>(act4, wfcp, fc_b, feats);

  rssm_scan3<<< Bn, 384, 0, stream >>>(actions, feats, eps,
                                       g_scan, g_wih2, g_pr2,
                                       gbih, gbhh, pr_b, po_b, (float*)d_out);
}

// Round 6
// 664.190 us; speedup vs baseline: 27.5192x; 1.0602x over previous
//
#include <hip/hip_runtime.h>
#include <math.h>

#define Bn 32
#define Tn 64
#define An 6
#define Ln 32
#define Hn 128
#define FDn 256
#define Nimg (Bn*Tn)   // 2048

typedef __attribute__((ext_vector_type(8))) short frag_ab;   // 8 bf16
typedef __attribute__((ext_vector_type(4))) float frag_cd;   // 4 fp32
typedef _Float16 h2_t __attribute__((ext_vector_type(2)));

__device__ __forceinline__ float sigmoid_fast(float x){
  return __builtin_amdgcn_rcpf(1.f + __expf(-x));
}
__device__ __forceinline__ float tanh_fast(float x){
  float x2 = fminf(fmaxf(2.f*x, -30.f), 30.f);
  float e = __expf(x2);
  return (e - 1.f) * __builtin_amdgcn_rcpf(e + 1.f);
}

__device__ __forceinline__ unsigned short f2bf(float f){
  unsigned int u = __float_as_uint(f);
  unsigned int r = (u + 0x7fffu + ((u >> 16) & 1u)) >> 16;
  return (unsigned short)r;
}
__device__ __forceinline__ unsigned packh(float a, float b){
  union { h2_t h; unsigned u; } x;
  x.h = (h2_t){(_Float16)a, (_Float16)b};
  return x.u;
}
__device__ __forceinline__ float fdot2u(unsigned a, unsigned b, float c){
  union { unsigned u; h2_t h; } ua, ub;
  ua.u = a; ub.u = b;
#if __has_builtin(__builtin_amdgcn_fdot2)
  return __builtin_amdgcn_fdot2(ua.h, ub.h, c, false);
#else
  return c + (float)ua.h.x*(float)ub.h.x + (float)ua.h.y*(float)ub.h.y;
#endif
}
// barrier without vmcnt drain: global stores in-flight are never read in-kernel
#define BAR_LDS() asm volatile("s_waitcnt lgkmcnt(0)\n\ts_barrier" ::: "memory")

// ---------------------------------------------------------------------------
// states: (2048, 3, 64, 64) fp32 NCHW -> (2048, 64, 64, 4) bf16 NHWC (c3 = 0)
// ---------------------------------------------------------------------------
__global__ void __launch_bounds__(256)
states_nhwc_kernel(const float* __restrict__ src, unsigned short* __restrict__ dst)
{
  int idx = blockIdx.x*256 + threadIdx.x;      // 2048*4096
  int n = idx >> 12, pix = idx & 4095;
  const float* s = src + (size_t)n*3*4096 + pix;
  union { unsigned short e[4]; uint2 v; } u;
  u.e[0] = f2bf(s[0]); u.e[1] = f2bf(s[4096]); u.e[2] = f2bf(s[8192]); u.e[3] = 0;
  *(uint2*)(dst + (size_t)idx*4) = u.v;
}

// ---------------------------------------------------------------------------
// Scan weight image layout (f16 pairs, uints):
#define WHH4_U 24576
#define PO4_U  (64*53*4)        // 13568
#define SCAN_U (WHH4_U + PO4_U) // 38144 uints

// merged prep: conv/fc weight permute->bf16 (tap-major, c-fast) + scan f16 packs
__global__ void __launch_bounds__(256)
prep2_kernel(const float* __restrict__ c1w, const float* __restrict__ c2w,
             const float* __restrict__ c3w, const float* __restrict__ c4w,
             const float* __restrict__ fcw,
             const float* __restrict__ gwhh, const float* __restrict__ gwih,
             const float* __restrict__ prw,  const float* __restrict__ pow_,
             unsigned short* __restrict__ w1p, unsigned short* __restrict__ w2p,
             unsigned short* __restrict__ w3p, unsigned short* __restrict__ w4p,
             unsigned short* __restrict__ wfcp,
             unsigned* __restrict__ g_scan, unsigned* __restrict__ g_wih2,
             unsigned* __restrict__ g_pr2)
{
  const int bid = blockIdx.x, tid = threadIdx.x;
  if (bid < 128){            // c2: (64,32,16) -> [k][tap*32+c]
    int idx = bid*256+tid;
    int k = idx >> 9, r = idx & 511, tap = r >> 5, c = r & 31;
    w2p[idx] = f2bf(c2w[k*512 + c*16 + tap]);
  } else if (bid < 640){     // c3: (128,64,16)
    int idx = (bid-128)*256+tid;
    int k = idx >> 10, r = idx & 1023, tap = r >> 6, c = r & 63;
    w3p[idx] = f2bf(c3w[k*1024 + c*16 + tap]);
  } else if (bid < 2688){    // c4: (256,128,16)
    int idx = (bid-640)*256+tid;
    int k = idx >> 11, r = idx & 2047, tap = r >> 7, c = r & 127;
    w4p[idx] = f2bf(c4w[k*2048 + c*16 + tap]);
  } else if (bid < 6784){    // fc: [o][sp*256+c] = src[o*4096 + c*16 + sp]
    int idx = (bid-2688)*256+tid;
    int o = idx >> 12, r = idx & 4095, sp = r >> 8, c = r & 255;
    wfcp[idx] = f2bf(fcw[o*4096 + c*16 + sp]);
  } else if (bid < 6792){    // c1: (32,3,16) -> [k][tap*4+c], c3=0
    int idx = (bid-6784)*256+tid;
    int k = idx >> 6, r = idx & 63, tap = r >> 2, c = r & 3;
    w1p[idx] = (c < 3) ? f2bf(c1w[k*48 + c*16 + tap]) : (unsigned short)0;
  } else if (bid < 6888){    // whh pack: 24576 uints
    int idx = (bid-6792)*256+tid;
    int q = idx & 3, r2 = idx >> 2;
    int k8 = r2 / 384, i = r2 - k8*384;
    int k = 8*k8 + 2*q;
    g_scan[idx] = packh(gwhh[i*128 + k], gwhh[i*128 + k + 1]);
  } else if (bid < 6917){    // wih pack: 7296 uints
    int idx = (bid-6888)*256+tid;
    if (idx < 19*384){
      int c = idx / 384, i = idx - c*384;
      g_wih2[idx] = packh(gwih[i*38 + 2*c], gwih[i*38 + 2*c + 1]);
    }
  } else if (bid < 6933){    // prior pack: 4096 uints
    int idx = (bid-6917)*256+tid;
    int o = idx >> 6, c = idx & 63;
    g_pr2[idx] = packh(prw[o*128 + 2*c], prw[o*128 + 2*c + 1]);
  } else {                   // post pack: 12288 entries
    int idx = (bid-6933)*256+tid;
    if (idx < 64*192){
      int o = idx / 192, r2 = idx - o*192;
      int u = r2 >> 2, q = r2 & 3;
      int j = u / 12, kk = u - j*12;
      int k = 96*j + 8*kk + 2*q;
      g_scan[WHH4_U + (o*53 + j*13 + kk)*4 + q] =
        packh(pow_[o*384 + k], pow_[o*384 + k + 1]);
    }
  }
}

// ---------------------------------------------------------------------------
// NHWC implicit-GEMM conv (k=4, s=2, p=1), MFMA 16x16x32 bf16. (unchanged R4)
// ---------------------------------------------------------------------------
template<int Cin, int IN, int Kout, int OUT, int BN, int LOG_SPB>
__global__ void __launch_bounds__(256)
convN_mfma(const unsigned short* __restrict__ in,
           const unsigned short* __restrict__ wB,
           const float* __restrict__ bias,
           unsigned short* __restrict__ out)
{
  constexpr int SPB = OUT*OUT;
  constexpr int KD  = 16*Cin;
  constexpr int NCH = KD/32;
  constexpr int NFN = BN/32;
  __shared__ __align__(16) unsigned short Alds[8*512];
  __shared__ __align__(16) unsigned short Blds[(BN/16)*512];

  const int tid = threadIdx.x;
  const int wave = tid >> 6, lane = tid & 63;
  const unsigned m0 = blockIdx.x * 128;
  const int n0 = blockIdx.y * BN;

  const int p = tid & 3;
  const unsigned short* baseA[2]; int oyA[2], oxA[2]; unsigned short* Adst[2];
#pragma unroll
  for (int h = 0; h < 2; h++){
    int r = (tid >> 2) + h*64;
    unsigned m = m0 + r;
    int nimg = m >> LOG_SPB;
    int sp = m & (SPB - 1);
    oyA[h] = sp / OUT; oxA[h] = sp & (OUT - 1);
    baseA[h] = in + (size_t)nimg * IN * IN * Cin;
    Adst[h] = &Alds[((r >> 4) << 9) + ((r & 15) << 3) + (p << 7)];
  }

  const int bn = tid >> 2, pb = tid & 3;
  const bool bAct = tid < BN*4;
  const unsigned short* Bsrc0 = wB + (size_t)(n0 + bn)*KD + pb*8;
  unsigned short* Bdst = &Blds[((bn >> 4) << 9) + ((bn & 15) << 3) + (pb << 7)];

  const int mhalf = wave >> 1, nhalf = wave & 1;
  frag_cd acc[4][NFN];
#pragma unroll
  for (int i = 0; i < 4; i++)
#pragma unroll
    for (int j = 0; j < NFN; j++) acc[i][j] = (frag_cd){0.f,0.f,0.f,0.f};

  auto loadA = [&](int kt, int h) -> uint4 {
    if constexpr (Cin >= 32){
      constexpr int CPT = Cin/32;
      int tap = kt / CPT;
      int c0 = (kt - tap*CPT)*32;
      int kh = tap >> 2, kw = tap & 3;
      int iy = 2*oyA[h] - 1 + kh;
      int ix = 2*oxA[h] - 1 + kw;
      uint4 v = {0u,0u,0u,0u};
      if ((unsigned)iy < (unsigned)IN && (unsigned)ix < (unsigned)IN)
        v = *(const uint4*)(baseA[h] + ((iy*IN + ix)*Cin + c0 + p*8));
      return v;
    } else {
      int kh = kt*2 + (p >> 1);
      int kw0 = (p & 1)*2;
      int iy = 2*oyA[h] - 1 + kh;
      int ix0 = 2*oxA[h] - 1 + kw0;
      union { uint2 u2[2]; uint4 u4; } v; v.u4 = (uint4){0u,0u,0u,0u};
      bool iyok = (unsigned)iy < (unsigned)IN;
      const unsigned short* rowp = baseA[h] + iy*IN*4;
#pragma unroll
      for (int d = 0; d < 2; d++){
        int ix = ix0 + d;
        if (iyok && (unsigned)ix < (unsigned)IN) v.u2[d] = *(const uint2*)(rowp + ix*4);
      }
      return v.u4;
    }
  };

  uint4 aPre0 = loadA(0,0), aPre1 = loadA(0,1);
  uint4 bPre = bAct ? *(const uint4*)Bsrc0 : (uint4){0u,0u,0u,0u};

#pragma unroll 1
  for (int kt = 0; kt < NCH; kt++){
    *(uint4*)Adst[0] = aPre0;
    *(uint4*)Adst[1] = aPre1;
    if (bAct) *(uint4*)Bdst = bPre;
    __syncthreads();
    if (kt + 1 < NCH){
      aPre0 = loadA(kt+1, 0);
      aPre1 = loadA(kt+1, 1);
      if (bAct) bPre = *(const uint4*)(Bsrc0 + (kt+1)*32);
    }
    frag_ab a[4], bf[NFN];
#pragma unroll
    for (int i = 0; i < 4; i++)
      a[i] = *(const frag_ab*)&Alds[(((mhalf<<2) + i) << 9) + lane*8];
#pragma unroll
    for (int j = 0; j < NFN; j++)
      bf[j] = *(const frag_ab*)&Blds[((nhalf*NFN + j) << 9) + lane*8];
#pragma unroll
    for (int i = 0; i < 4; i++)
#pragma unroll
      for (int j = 0; j < NFN; j++)
        acc[i][j] = __builtin_amdgcn_mfma_f32_16x16x32_bf16(a[i], bf[j], acc[i][j], 0, 0, 0);
    __syncthreads();
  }

  const unsigned mb = m0 + mhalf*64 + ((lane >> 4) << 2);
#pragma unroll
  for (int j = 0; j < NFN; j++){
    const int kg = n0 + nhalf*(NFN*16) + j*16 + (lane & 15);
    const float bv = bias[kg];
#pragma unroll
    for (int i = 0; i < 4; i++){
#pragma unroll
      for (int r = 0; r < 4; r++){
        unsigned mg = mb + i*16 + r;
        out[(size_t)mg*Kout + kg] = f2bf(fmaxf(acc[i][j][r] + bv, 0.f));
      }
    }
  }
}

// ---------------------------------------------------------------------------
// FC GEMM (unchanged R4)
// ---------------------------------------------------------------------------
__global__ void __launch_bounds__(256)
fc_mfma2(const unsigned short* __restrict__ A, const unsigned short* __restrict__ wB,
         const float* __restrict__ bias, float* __restrict__ outF)
{
  constexpr int KD = 4096, NCH = KD/32;
  __shared__ __align__(16) unsigned short Alds[4*512];
  __shared__ __align__(16) unsigned short Blds[4*512];

  const int tid = threadIdx.x, wave = tid >> 6, lane = tid & 63;
  const int m0 = blockIdx.x * 64, n0 = blockIdx.y * 64;
  const int r = tid >> 2, pc = tid & 3;
  const unsigned short* Asrc = A + (size_t)(m0 + r)*KD + pc*8;
  const unsigned short* Bsrc = wB + (size_t)(n0 + r)*KD + pc*8;
  unsigned short* Adst = &Alds[((r >> 4) << 9) + ((r & 15) << 3) + (pc << 7)];
  unsigned short* Bdst = &Blds[((r >> 4) << 9) + ((r & 15) << 3) + (pc << 7)];
  const int mh = wave >> 1, nh = wave & 1;

  frag_cd acc[2][2];
#pragma unroll
  for (int i = 0; i < 2; i++)
#pragma unroll
    for (int j = 0; j < 2; j++) acc[i][j] = (frag_cd){0.f,0.f,0.f,0.f};

  uint4 aP = *(const uint4*)Asrc, bP = *(const uint4*)Bsrc;
#pragma unroll 1
  for (int kt = 0; kt < NCH; kt++){
    *(uint4*)Adst = aP;
    *(uint4*)Bdst = bP;
    __syncthreads();
    if (kt + 1 < NCH){
      aP = *(const uint4*)(Asrc + (kt+1)*32);
      bP = *(const uint4*)(Bsrc + (kt+1)*32);
    }
    frag_ab a[2], b[2];
#pragma unroll
    for (int i = 0; i < 2; i++) a[i] = *(const frag_ab*)&Alds[(((mh<<1)+i) << 9) + lane*8];
#pragma unroll
    for (int j = 0; j < 2; j++) b[j] = *(const frag_ab*)&Blds[(((nh<<1)+j) << 9) + lane*8];
#pragma unroll
    for (int i = 0; i < 2; i++)
#pragma unroll
      for (int j = 0; j < 2; j++)
        acc[i][j] = __builtin_amdgcn_mfma_f32_16x16x32_bf16(a[i], b[j], acc[i][j], 0, 0, 0);
    __syncthreads();
  }

  const int mb = m0 + mh*32 + ((lane >> 4) << 2);
#pragma unroll
  for (int j = 0; j < 2; j++){
    const int kg = n0 + nh*32 + j*16 + (lane & 15);
    const float bv = bias[kg];
#pragma unroll
    for (int i = 0; i < 2; i++)
#pragma unroll
      for (int rr = 0; rr < 4; rr++)
        outF[(size_t)(mb + i*16 + rr)*256 + kg] = acc[i][j][rr] + bv;
  }
}

// ---------------------------------------------------------------------------
// RSSM scan v4: ALL weights VGPR-resident (whh col 16xuint4, post row-quarter
// 12xuint4, prior 32xuint, wih 19xuint per thread). LDS only for h/f/x/gates
// (~4 KB). Fast activations (v_exp_f32 + rcp) on the serial path.
// ---------------------------------------------------------------------------
__global__ void __launch_bounds__(384)
rssm_scan4(const float* __restrict__ actions, const float* __restrict__ feats,
           const float* __restrict__ eps,
           const unsigned* __restrict__ g_scan,   // whh4 ++ po4
           const unsigned* __restrict__ g_wih2,   // [19][384]
           const unsigned* __restrict__ g_pr2,    // [64][64]
           const float* __restrict__ bih,  const float* __restrict__ bhh,
           const float* __restrict__ prior_b, const float* __restrict__ post_b,
           float* __restrict__ out)
{
  __shared__ __align__(16) _Float16 sh_hfh[384];   // [0,128)=h, [128,384)=f
  __shared__ __align__(16) _Float16 sh_xh[40];     // [0,32)=z, [32,38)=a
  __shared__ __align__(16) float sh_gi[384];
  __shared__ __align__(16) float sh_gh[384];

  const int b = blockIdx.x, tid = threadIdx.x;

  // ---- load thread-private weights into registers (once) ----
  uint4 whhr[16];
  {
    const uint4* src = (const uint4*)g_scan;   // [k8][384]
#pragma unroll
    for (int k8 = 0; k8 < 16; k8++) whhr[k8] = src[k8*384 + tid];
  }
  unsigned wih[19];
#pragma unroll
  for (int c = 0; c < 19; c++) wih[c] = g_wih2[c*384 + tid];

  unsigned prw[32];
  float prb = 0.f;
  if (tid < 128){
    const unsigned* src = g_pr2 + (tid >> 1)*64 + (tid & 1)*32;
#pragma unroll
    for (int c = 0; c < 32; c++) prw[c] = src[c];
    prb = prior_b[tid >> 1];
  }

  int om = 0, pj = 0, o_p = 0; bool is_mu = false; float pob = 0.f;
  uint4 pww[12];
  if (tid >= 128){
    const int tt = tid - 128;
    om = tt >> 2; pj = tt & 3;
    o_p = (om >> 1) + (om & 1)*32;
    is_mu = !(om & 1);
    pob = post_b[o_p];
    const uint4* src = (const uint4*)(g_scan + WHH4_U) + o_p*53 + pj*13;
#pragma unroll
    for (int kk = 0; kk < 12; kk++) pww[kk] = src[kk];
  }

  const float bih_i = bih[tid], bhh_i = bhh[tid];
  float hreg = 0.f;

  {
    const int bt0 = b*Tn;
    if (tid < Hn) sh_hfh[tid] = (_Float16)0.f;
    if (tid < Ln) sh_xh[tid] = (_Float16)0.f;
    if (tid >= 32 && tid < 38) sh_xh[tid] = (_Float16)actions[(size_t)bt0*An + (tid-32)];
    if (tid >= 64 && tid < 320) sh_hfh[128 + tid - 64] = (_Float16)feats[(size_t)bt0*FDn + (tid-64)];
  }
  __syncthreads();

  const uint4* H4   = (const uint4*)sh_hfh;
  const unsigned* X2 = (const unsigned*)sh_xh;

  const int OFF_MUP = 0;
  const int OFF_LVP = Bn*Tn*Ln;
  const int OFF_MUQ = 2*Bn*Tn*Ln;
  const int OFF_LVQ = 3*Bn*Tn*Ln;
  const int OFF_H   = 4*Bn*Tn*Ln;
  const int OFF_Z   = 4*Bn*Tn*Ln + Bn*Tn*Hn;

  float freg = 0.f, areg = 0.f, epsr = 0.f;

  for (int t = 0; t < Tn; t++){
    const int bt = b*Tn + t;

    // write f_t staged last iter (t>0); prefetch t+1 inputs; eps_t
    if (t > 0 && tid >= 64 && tid < 320) sh_hfh[128 + tid - 64] = (_Float16)freg;
    if (t < Tn-1){
      if (tid >= 64 && tid < 320) freg = feats[(size_t)(bt+1)*FDn + (tid-64)];
      if (tid >= 320 && tid < 326) areg = actions[(size_t)(bt+1)*An + (tid-320)];
    }
    if (tid >= 128 && ((tid-128)&7) == 0) epsr = eps[(size_t)bt*Ln + ((tid-128)>>3)];

    // ---- phase A: gates (all 384 threads, weights in regs) ----
    {
      float a0 = bih_i, a1 = 0.f;
#pragma unroll
      for (int c = 0; c < 19; c += 2) a0 = fdot2u(wih[c], X2[c], a0);
#pragma unroll
      for (int c = 1; c < 19; c += 2) a1 = fdot2u(wih[c], X2[c], a1);
      sh_gi[tid] = a0 + a1;

      float g0 = bhh_i, g1 = 0.f, g2 = 0.f, g3 = 0.f;
#pragma unroll
      for (int k8 = 0; k8 < 16; k8++){
        uint4 w = whhr[k8];
        uint4 h = H4[k8];
        g0 = fdot2u(w.x, h.x, g0);
        g1 = fdot2u(w.y, h.y, g1);
        g2 = fdot2u(w.z, h.z, g2);
        g3 = fdot2u(w.w, h.w, g3);
      }
      sh_gh[tid] = (g0 + g1) + (g2 + g3);
    }
    BAR_LDS();

    // ---- combine: new h ----
    if (tid < Hn){
      const float r  = sigmoid_fast(sh_gi[tid]       + sh_gh[tid]);
      const float zg = sigmoid_fast(sh_gi[Hn  + tid] + sh_gh[Hn  + tid]);
      const float nn = tanh_fast(fmaf(r, sh_gh[2*Hn + tid], sh_gi[2*Hn + tid]));
      hreg = (1.f - zg)*nn + zg*hreg;
      sh_hfh[tid] = (_Float16)hreg;
      out[OFF_H + (size_t)bt*Hn + tid] = hreg;
    }
    if (t < Tn-1 && tid >= 320 && tid < 326) sh_xh[32 + tid - 320] = (_Float16)areg;
    BAR_LDS();

    // ---- phase B: prior / posterior (+in-wave reparam) ----
    if (tid < 128){
      const int j = tid & 1;
      float a0 = 0.f, a1 = 0.f, a2 = 0.f, a3 = 0.f;
#pragma unroll
      for (int c4 = 0; c4 < 8; c4++){
        uint4 h = H4[8*j + c4];
        a0 = fdot2u(prw[4*c4+0], h.x, a0);
        a1 = fdot2u(prw[4*c4+1], h.y, a1);
        a2 = fdot2u(prw[4*c4+2], h.z, a2);
        a3 = fdot2u(prw[4*c4+3], h.w, a3);
      }
      float p = (a0 + a1) + (a2 + a3);
      p += __shfl_xor(p, 1);
      if (j == 0){
        const int o = tid >> 1;
        p += prb;
        if (o < Ln) out[OFF_MUP + (size_t)bt*Ln + o] = p;
        else        out[OFF_LVP + (size_t)bt*Ln + (o - Ln)] = p;
      }
    } else {
      float a0 = 0.f, a1 = 0.f, a2 = 0.f, a3 = 0.f;
#pragma unroll
      for (int kk = 0; kk < 12; kk++){
        uint4 w = pww[kk];
        uint4 h = H4[pj*12 + kk];
        a0 = fdot2u(w.x, h.x, a0);
        a1 = fdot2u(w.y, h.y, a1);
        a2 = fdot2u(w.z, h.z, a2);
        a3 = fdot2u(w.w, h.w, a3);
      }
      float p = (a0 + a1) + (a2 + a3);
      p += __shfl_xor(p, 1);
      p += __shfl_xor(p, 2);
      p += pob;
      const float q_part = __shfl_xor(p, 4);
      if (pj == 0){
        if (is_mu){
          const int o = om >> 1;
          out[OFF_MUQ + (size_t)bt*Ln + o] = p;
          const float zz = fmaf(__expf(0.5f*q_part), epsr, p);
          sh_xh[o] = (_Float16)zz;
          out[OFF_Z + (size_t)bt*Ln + o] = zz;
        } else {
          out[OFF_LVQ + (size_t)bt*Ln + (o_p - Ln)] = p;
        }
      }
    }
    BAR_LDS();
  }
}

// ---------------------------------------------------------------------------
extern "C" void kernel_launch(void* const* d_in, const int* in_sizes, int n_in,
                              void* d_out, int out_size, void* d_ws, size_t ws_size,
                              hipStream_t stream)
{
  const float* states = (const float*)d_in[0];
  const float* actions= (const float*)d_in[1];
  const float* c1_w = (const float*)d_in[2];  const float* c1_b = (const float*)d_in[3];
  const float* c2_w = (const float*)d_in[4];  const float* c2_b = (const float*)d_in[5];
  const float* c3_w = (const float*)d_in[6];  const float* c3_b = (const float*)d_in[7];
  const float* c4_w = (const float*)d_in[8];  const float* c4_b = (const float*)d_in[9];
  const float* fc_w = (const float*)d_in[10]; const float* fc_b = (const float*)d_in[11];
  const float* gwih = (const float*)d_in[12]; const float* gwhh = (const float*)d_in[13];
  const float* gbih = (const float*)d_in[14]; const float* gbhh = (const float*)d_in[15];
  const float* pr_w = (const float*)d_in[16]; const float* pr_b = (const float*)d_in[17];
  const float* po_w = (const float*)d_in[18]; const float* po_b = (const float*)d_in[19];
  const float* eps  = (const float*)d_in[20];

  char* p = (char*)d_ws;
  auto alloc = [&](size_t bytes){ char* r = p; p += (bytes + 255) & ~255ULL; return r; };

  unsigned short* statesB = (unsigned short*)alloc((size_t)Nimg*4096*4*2); // NHWC c=4
  unsigned short* act1    = (unsigned short*)alloc((size_t)Nimg*1024*32*2);
  unsigned short* act2    = (unsigned short*)alloc((size_t)Nimg*256*64*2);
  unsigned short* act3    = (unsigned short*)alloc((size_t)Nimg*64*128*2);
  unsigned short* act4    = (unsigned short*)alloc((size_t)Nimg*16*256*2);
  float*          feats   = (float*)alloc((size_t)Nimg*FDn*4);
  unsigned short* w1p     = (unsigned short*)alloc(32*64*2);
  unsigned short* w2p     = (unsigned short*)alloc((size_t)64*512*2);
  unsigned short* w3p     = (unsigned short*)alloc((size_t)128*1024*2);
  unsigned short* w4p     = (unsigned short*)alloc((size_t)256*2048*2);
  unsigned short* wfcp    = (unsigned short*)alloc((size_t)256*4096*2);
  unsigned* g_scan = (unsigned*)alloc((size_t)SCAN_U*4);
  unsigned* g_wih2 = (unsigned*)alloc((size_t)19*384*4);
  unsigned* g_pr2  = (unsigned*)alloc((size_t)64*64*4);

  states_nhwc_kernel<<<Nimg*4096/256, 256, 0, stream>>>(states, statesB);
  prep2_kernel<<<6981, 256, 0, stream>>>(c1_w, c2_w, c3_w, c4_w, fc_w,
                                         gwhh, gwih, pr_w, po_w,
                                         w1p, w2p, w3p, w4p, wfcp,
                                         g_scan, g_wih2, g_pr2);

  // encoder: NHWC implicit-GEMM MFMA convs (BM=128)
  convN_mfma<4,64,32,32,32,10>  <<< dim3(Nimg*1024/128, 1), 256, 0, stream >>>(statesB, w1p, c1_b, act1);
  convN_mfma<32,32,64,16,64,8>  <<< dim3(Nimg*256/128, 1), 256, 0, stream >>>(act1, w2p, c2_b, act2);
  convN_mfma<64,16,128,8,64,6>  <<< dim3(Nimg*64/128, 2), 256, 0, stream >>>(act2, w3p, c3_b, act3);
  convN_mfma<128,8,256,4,64,4>  <<< dim3(Nimg*16/128, 4), 256, 0, stream >>>(act3, w4p, c4_b, act4);

  fc_mfma2<<< dim3(Nimg/64, 4), 256, 0, stream >>>(act4, wfcp, fc_b, feats);

  rssm_scan4<<< Bn, 384, 0, stream >>>(actions, feats, eps,
                                       g_scan, g_wih2, g_pr2,
                                       gbih, gbhh, pr_b, po_b, (float*)d_out);
}

// Round 7
// 621.433 us; speedup vs baseline: 29.4126x; 1.0688x over previous
//
#include <hip/hip_runtime.h>
#include <math.h>

#define Bn 32
#define Tn 64
#define An 6
#define Ln 32
#define Hn 128
#define FDn 256
#define Nimg (Bn*Tn)   // 2048

typedef __attribute__((ext_vector_type(8))) short frag_ab;   // 8 bf16
typedef __attribute__((ext_vector_type(4))) float frag_cd;   // 4 fp32
typedef _Float16 h2_t __attribute__((ext_vector_type(2)));

__device__ __forceinline__ float sigmoid_fast(float x){
  return __builtin_amdgcn_rcpf(1.f + __expf(-x));
}
__device__ __forceinline__ float tanh_fast(float x){
  float x2 = fminf(fmaxf(2.f*x, -30.f), 30.f);
  float e = __expf(x2);
  return (e - 1.f) * __builtin_amdgcn_rcpf(e + 1.f);
}

__device__ __forceinline__ unsigned short f2bf(float f){
  unsigned int u = __float_as_uint(f);
  unsigned int r = (u + 0x7fffu + ((u >> 16) & 1u)) >> 16;
  return (unsigned short)r;
}
__device__ __forceinline__ unsigned packh(float a, float b){
  union { h2_t h; unsigned u; } x;
  x.h = (h2_t){(_Float16)a, (_Float16)b};
  return x.u;
}
__device__ __forceinline__ float fdot2u(unsigned a, unsigned b, float c){
  union { unsigned u; h2_t h; } ua, ub;
  ua.u = a; ub.u = b;
#if __has_builtin(__builtin_amdgcn_fdot2)
  return __builtin_amdgcn_fdot2(ua.h, ub.h, c, false);
#else
  return c + (float)ua.h.x*(float)ub.h.x + (float)ua.h.y*(float)ub.h.y;
#endif
}
// barrier without vmcnt drain: global loads/stores in flight stay in flight
#define BAR_LDS() asm volatile("s_waitcnt lgkmcnt(0)\n\ts_barrier" ::: "memory")

// LDS fragment addressing with XOR row swizzle (units: unsigned short)
//  write: row r (within tile), k-piece p (8 bf16) of a 16x32 fragment
__device__ __forceinline__ int swz_w(int r, int p){
  return ((r >> 4) << 9) + (p << 7) + ((((r & 15) ^ (p << 2))) << 3);
}
//  read: fragment f, lane l  (row = l&15, piece = l>>4)
__device__ __forceinline__ int swz_r(int f, int l){
  return (f << 9) + ((l >> 4) << 7) + ((((l & 15) ^ ((l >> 4) << 2))) << 3);
}

// ---------------------------------------------------------------------------
// states: (2048, 3, 64, 64) fp32 NCHW -> (2048, 64, 64, 4) bf16 NHWC (c3 = 0)
// ---------------------------------------------------------------------------
__global__ void __launch_bounds__(256)
states_nhwc_kernel(const float* __restrict__ src, unsigned short* __restrict__ dst)
{
  int idx = blockIdx.x*256 + threadIdx.x;      // 2048*4096
  int n = idx >> 12, pix = idx & 4095;
  const float* s = src + (size_t)n*3*4096 + pix;
  union { unsigned short e[4]; uint2 v; } u;
  u.e[0] = f2bf(s[0]); u.e[1] = f2bf(s[4096]); u.e[2] = f2bf(s[8192]); u.e[3] = 0;
  *(uint2*)(dst + (size_t)idx*4) = u.v;
}

// ---------------------------------------------------------------------------
// Scan weight image layout (f16 pairs, uints):
#define WHH4_U 24576
#define PO4_U  (64*53*4)        // 13568
#define SCAN_U (WHH4_U + PO4_U) // 38144 uints

// merged prep: conv/fc weight permute->bf16 (tap-major, c-fast) + scan f16 packs
__global__ void __launch_bounds__(256)
prep2_kernel(const float* __restrict__ c1w, const float* __restrict__ c2w,
             const float* __restrict__ c3w, const float* __restrict__ c4w,
             const float* __restrict__ fcw,
             const float* __restrict__ gwhh, const float* __restrict__ gwih,
             const float* __restrict__ prw,  const float* __restrict__ pow_,
             unsigned short* __restrict__ w1p, unsigned short* __restrict__ w2p,
             unsigned short* __restrict__ w3p, unsigned short* __restrict__ w4p,
             unsigned short* __restrict__ wfcp,
             unsigned* __restrict__ g_scan, unsigned* __restrict__ g_wih2,
             unsigned* __restrict__ g_pr2)
{
  const int bid = blockIdx.x, tid = threadIdx.x;
  if (bid < 128){            // c2: (64,32,16) -> [k][tap*32+c]
    int idx = bid*256+tid;
    int k = idx >> 9, r = idx & 511, tap = r >> 5, c = r & 31;
    w2p[idx] = f2bf(c2w[k*512 + c*16 + tap]);
  } else if (bid < 640){     // c3: (128,64,16)
    int idx = (bid-128)*256+tid;
    int k = idx >> 10, r = idx & 1023, tap = r >> 6, c = r & 63;
    w3p[idx] = f2bf(c3w[k*1024 + c*16 + tap]);
  } else if (bid < 2688){    // c4: (256,128,16)
    int idx = (bid-640)*256+tid;
    int k = idx >> 11, r = idx & 2047, tap = r >> 7, c = r & 127;
    w4p[idx] = f2bf(c4w[k*2048 + c*16 + tap]);
  } else if (bid < 6784){    // fc: [o][sp*256+c] = src[o*4096 + c*16 + sp]
    int idx = (bid-2688)*256+tid;
    int o = idx >> 12, r = idx & 4095, sp = r >> 8, c = r & 255;
    wfcp[idx] = f2bf(fcw[o*4096 + c*16 + sp]);
  } else if (bid < 6792){    // c1: (32,3,16) -> [k][tap*4+c], c3=0
    int idx = (bid-6784)*256+tid;
    int k = idx >> 6, r = idx & 63, tap = r >> 2, c = r & 3;
    w1p[idx] = (c < 3) ? f2bf(c1w[k*48 + c*16 + tap]) : (unsigned short)0;
  } else if (bid < 6888){    // whh pack: 24576 uints
    int idx = (bid-6792)*256+tid;
    int q = idx & 3, r2 = idx >> 2;
    int k8 = r2 / 384, i = r2 - k8*384;
    int k = 8*k8 + 2*q;
    g_scan[idx] = packh(gwhh[i*128 + k], gwhh[i*128 + k + 1]);
  } else if (bid < 6917){    // wih pack: 7296 uints
    int idx = (bid-6888)*256+tid;
    if (idx < 19*384){
      int c = idx / 384, i = idx - c*384;
      g_wih2[idx] = packh(gwih[i*38 + 2*c], gwih[i*38 + 2*c + 1]);
    }
  } else if (bid < 6933){    // prior pack: 4096 uints
    int idx = (bid-6917)*256+tid;
    int o = idx >> 6, c = idx & 63;
    g_pr2[idx] = packh(prw[o*128 + 2*c], prw[o*128 + 2*c + 1]);
  } else {                   // post pack: 12288 entries
    int idx = (bid-6933)*256+tid;
    if (idx < 64*192){
      int o = idx / 192, r2 = idx - o*192;
      int u = r2 >> 2, q = r2 & 3;
      int j = u / 12, kk = u - j*12;
      int k = 96*j + 8*kk + 2*q;
      g_scan[WHH4_U + (o*53 + j*13 + kk)*4 + q] =
        packh(pow_[o*384 + k], pow_[o*384 + k + 1]);
    }
  }
}

// ---------------------------------------------------------------------------
// NHWC implicit-GEMM conv (k=4, s=2, p=1), MFMA 16x16x32 bf16.
// v2: XOR-swizzled LDS (write 2-way max = free, read bijective) + LDS
// double-buffer with ONE lgkm-only barrier per chunk; global prefetch stays
// in flight across the barrier (2-deep).
// ---------------------------------------------------------------------------
template<int Cin, int IN, int Kout, int OUT, int BN, int LOG_SPB>
__global__ void __launch_bounds__(256)
convN_mfma(const unsigned short* __restrict__ in,
           const unsigned short* __restrict__ wB,
           const float* __restrict__ bias,
           unsigned short* __restrict__ out)
{
  constexpr int SPB = OUT*OUT;
  constexpr int KD  = 16*Cin;
  constexpr int NCH = KD/32;
  constexpr int NFN = BN/32;
  constexpr int BFR = BN/16;
  __shared__ __align__(16) unsigned short Alds[2][8*512];
  __shared__ __align__(16) unsigned short Blds[2][BFR*512];

  const int tid = threadIdx.x;
  const int wave = tid >> 6, lane = tid & 63;
  const unsigned m0 = blockIdx.x * 128;
  const int n0 = blockIdx.y * BN;

  const int p = tid & 3;
  const unsigned short* baseA[2]; int oyA[2], oxA[2]; int AdstI[2];
#pragma unroll
  for (int h = 0; h < 2; h++){
    int r = (tid >> 2) + h*64;
    unsigned m = m0 + r;
    int nimg = m >> LOG_SPB;
    int sp = m & (SPB - 1);
    oyA[h] = sp / OUT; oxA[h] = sp & (OUT - 1);
    baseA[h] = in + (size_t)nimg * IN * IN * Cin;
    AdstI[h] = swz_w(r, p);
  }

  const int bn = tid >> 2, pb = tid & 3;
  const bool bAct = tid < BN*4;
  const unsigned short* Bsrc0 = wB + (size_t)(n0 + bn)*KD + pb*8;
  const int BdstI = swz_w(bn, pb);

  const int mhalf = wave >> 1, nhalf = wave & 1;
  frag_cd acc[4][NFN];
#pragma unroll
  for (int i = 0; i < 4; i++)
#pragma unroll
    for (int j = 0; j < NFN; j++) acc[i][j] = (frag_cd){0.f,0.f,0.f,0.f};

  auto loadA = [&](int kt, int h) -> uint4 {
    if constexpr (Cin >= 32){
      constexpr int CPT = Cin/32;
      int tap = kt / CPT;
      int c0 = (kt - tap*CPT)*32;
      int kh = tap >> 2, kw = tap & 3;
      int iy = 2*oyA[h] - 1 + kh;
      int ix = 2*oxA[h] - 1 + kw;
      uint4 v = {0u,0u,0u,0u};
      if ((unsigned)iy < (unsigned)IN && (unsigned)ix < (unsigned)IN)
        v = *(const uint4*)(baseA[h] + ((iy*IN + ix)*Cin + c0 + p*8));
      return v;
    } else {
      int kh = kt*2 + (p >> 1);
      int kw0 = (p & 1)*2;
      int iy = 2*oyA[h] - 1 + kh;
      int ix0 = 2*oxA[h] - 1 + kw0;
      union { uint2 u2[2]; uint4 u4; } v; v.u4 = (uint4){0u,0u,0u,0u};
      bool iyok = (unsigned)iy < (unsigned)IN;
      const unsigned short* rowp = baseA[h] + iy*IN*4;
#pragma unroll
      for (int d = 0; d < 2; d++){
        int ix = ix0 + d;
        if (iyok && (unsigned)ix < (unsigned)IN) v.u2[d] = *(const uint2*)(rowp + ix*4);
      }
      return v.u4;
    }
  };

  const int rdoff = swz_r(0, lane);

  // prologue: stage chunk 0 into buf 0; prefetch chunk 1
  uint4 aR0 = loadA(0,0), aR1 = loadA(0,1);
  uint4 bR = bAct ? *(const uint4*)Bsrc0 : (uint4){0u,0u,0u,0u};
  *(uint4*)&Alds[0][AdstI[0]] = aR0;
  *(uint4*)&Alds[0][AdstI[1]] = aR1;
  if (bAct) *(uint4*)&Blds[0][BdstI] = bR;
  if (NCH > 1){
    aR0 = loadA(1,0); aR1 = loadA(1,1);
    if (bAct) bR = *(const uint4*)(Bsrc0 + 32);
  }
  BAR_LDS();

#pragma unroll 2
  for (int kt = 0; kt < NCH; kt++){
    const int cur = kt & 1, nxt = cur ^ 1;
    if (kt + 1 < NCH){
      *(uint4*)&Alds[nxt][AdstI[0]] = aR0;
      *(uint4*)&Alds[nxt][AdstI[1]] = aR1;
      if (bAct) *(uint4*)&Blds[nxt][BdstI] = bR;
      if (kt + 2 < NCH){
        aR0 = loadA(kt+2, 0);
        aR1 = loadA(kt+2, 1);
        if (bAct) bR = *(const uint4*)(Bsrc0 + (kt+2)*32);
      }
    }
    frag_ab a[4], bf[NFN];
#pragma unroll
    for (int i = 0; i < 4; i++)
      a[i] = *(const frag_ab*)&Alds[cur][(((mhalf<<2) + i) << 9) + rdoff];
#pragma unroll
    for (int j = 0; j < NFN; j++)
      bf[j] = *(const frag_ab*)&Blds[cur][((nhalf*NFN + j) << 9) + rdoff];
#pragma unroll
    for (int i = 0; i < 4; i++)
#pragma unroll
      for (int j = 0; j < NFN; j++)
        acc[i][j] = __builtin_amdgcn_mfma_f32_16x16x32_bf16(a[i], bf[j], acc[i][j], 0, 0, 0);
    BAR_LDS();
  }

  const unsigned mb = m0 + mhalf*64 + ((lane >> 4) << 2);
#pragma unroll
  for (int j = 0; j < NFN; j++){
    const int kg = n0 + nhalf*(NFN*16) + j*16 + (lane & 15);
    const float bv = bias[kg];
#pragma unroll
    for (int i = 0; i < 4; i++){
#pragma unroll
      for (int r = 0; r < 4; r++){
        unsigned mg = mb + i*16 + r;
        out[(size_t)mg*Kout + kg] = f2bf(fmaxf(acc[i][j][r] + bv, 0.f));
      }
    }
  }
}

// ---------------------------------------------------------------------------
// FC GEMM: A (2048 x 4096) bf16, W (256 x 4096) permuted. Same swizzle+dbuf.
// ---------------------------------------------------------------------------
__global__ void __launch_bounds__(256)
fc_mfma2(const unsigned short* __restrict__ A, const unsigned short* __restrict__ wB,
         const float* __restrict__ bias, float* __restrict__ outF)
{
  constexpr int KD = 4096, NCH = KD/32;
  __shared__ __align__(16) unsigned short Alds[2][4*512];
  __shared__ __align__(16) unsigned short Blds[2][4*512];

  const int tid = threadIdx.x, wave = tid >> 6, lane = tid & 63;
  const int m0 = blockIdx.x * 64, n0 = blockIdx.y * 64;
  const int r = tid >> 2, pc = tid & 3;
  const unsigned short* Asrc = A + (size_t)(m0 + r)*KD + pc*8;
  const unsigned short* Bsrc = wB + (size_t)(n0 + r)*KD + pc*8;
  const int wI = swz_w(r, pc);
  const int mh = wave >> 1, nh = wave & 1;
  const int rdoff = swz_r(0, lane);

  frag_cd acc[2][2];
#pragma unroll
  for (int i = 0; i < 2; i++)
#pragma unroll
    for (int j = 0; j < 2; j++) acc[i][j] = (frag_cd){0.f,0.f,0.f,0.f};

  uint4 aP = *(const uint4*)Asrc, bP = *(const uint4*)Bsrc;
  *(uint4*)&Alds[0][wI] = aP;
  *(uint4*)&Blds[0][wI] = bP;
  aP = *(const uint4*)(Asrc + 32);
  bP = *(const uint4*)(Bsrc + 32);
  BAR_LDS();

#pragma unroll 2
  for (int kt = 0; kt < NCH; kt++){
    const int cur = kt & 1, nxt = cur ^ 1;
    if (kt + 1 < NCH){
      *(uint4*)&Alds[nxt][wI] = aP;
      *(uint4*)&Blds[nxt][wI] = bP;
      if (kt + 2 < NCH){
        aP = *(const uint4*)(Asrc + (kt+2)*32);
        bP = *(const uint4*)(Bsrc + (kt+2)*32);
      }
    }
    frag_ab a[2], b[2];
#pragma unroll
    for (int i = 0; i < 2; i++) a[i] = *(const frag_ab*)&Alds[cur][(((mh<<1)+i) << 9) + rdoff];
#pragma unroll
    for (int j = 0; j < 2; j++) b[j] = *(const frag_ab*)&Blds[cur][(((nh<<1)+j) << 9) + rdoff];
#pragma unroll
    for (int i = 0; i < 2; i++)
#pragma unroll
      for (int j = 0; j < 2; j++)
        acc[i][j] = __builtin_amdgcn_mfma_f32_16x16x32_bf16(a[i], b[j], acc[i][j], 0, 0, 0);
    BAR_LDS();
  }

  const int mb = m0 + mh*32 + ((lane >> 4) << 2);
#pragma unroll
  for (int j = 0; j < 2; j++){
    const int kg = n0 + nh*32 + j*16 + (lane & 15);
    const float bv = bias[kg];
#pragma unroll
    for (int i = 0; i < 2; i++)
#pragma unroll
      for (int rr = 0; rr < 4; rr++)
        outF[(size_t)(mb + i*16 + rr)*256 + kg] = acc[i][j][rr] + bv;
  }
}

// ---------------------------------------------------------------------------
// RSSM scan v4 (unchanged from R5)
// ---------------------------------------------------------------------------
__global__ void __launch_bounds__(384)
rssm_scan4(const float* __restrict__ actions, const float* __restrict__ feats,
           const float* __restrict__ eps,
           const unsigned* __restrict__ g_scan,
           const unsigned* __restrict__ g_wih2,
           const unsigned* __restrict__ g_pr2,
           const float* __restrict__ bih,  const float* __restrict__ bhh,
           const float* __restrict__ prior_b, const float* __restrict__ post_b,
           float* __restrict__ out)
{
  __shared__ __align__(16) _Float16 sh_hfh[384];
  __shared__ __align__(16) _Float16 sh_xh[40];
  __shared__ __align__(16) float sh_gi[384];
  __shared__ __align__(16) float sh_gh[384];

  const int b = blockIdx.x, tid = threadIdx.x;

  uint4 whhr[16];
  {
    const uint4* src = (const uint4*)g_scan;
#pragma unroll
    for (int k8 = 0; k8 < 16; k8++) whhr[k8] = src[k8*384 + tid];
  }
  unsigned wih[19];
#pragma unroll
  for (int c = 0; c < 19; c++) wih[c] = g_wih2[c*384 + tid];

  unsigned prw[32];
  float prb = 0.f;
  if (tid < 128){
    const unsigned* src = g_pr2 + (tid >> 1)*64 + (tid & 1)*32;
#pragma unroll
    for (int c = 0; c < 32; c++) prw[c] = src[c];
    prb = prior_b[tid >> 1];
  }

  int om = 0, pj = 0, o_p = 0; bool is_mu = false; float pob = 0.f;
  uint4 pww[12];
  if (tid >= 128){
    const int tt = tid - 128;
    om = tt >> 2; pj = tt & 3;
    o_p = (om >> 1) + (om & 1)*32;
    is_mu = !(om & 1);
    pob = post_b[o_p];
    const uint4* src = (const uint4*)(g_scan + WHH4_U) + o_p*53 + pj*13;
#pragma unroll
    for (int kk = 0; kk < 12; kk++) pww[kk] = src[kk];
  }

  const float bih_i = bih[tid], bhh_i = bhh[tid];
  float hreg = 0.f;

  {
    const int bt0 = b*Tn;
    if (tid < Hn) sh_hfh[tid] = (_Float16)0.f;
    if (tid < Ln) sh_xh[tid] = (_Float16)0.f;
    if (tid >= 32 && tid < 38) sh_xh[tid] = (_Float16)actions[(size_t)bt0*An + (tid-32)];
    if (tid >= 64 && tid < 320) sh_hfh[128 + tid - 64] = (_Float16)feats[(size_t)bt0*FDn + (tid-64)];
  }
  __syncthreads();

  const uint4* H4   = (const uint4*)sh_hfh;
  const unsigned* X2 = (const unsigned*)sh_xh;

  const int OFF_MUP = 0;
  const int OFF_LVP = Bn*Tn*Ln;
  const int OFF_MUQ = 2*Bn*Tn*Ln;
  const int OFF_LVQ = 3*Bn*Tn*Ln;
  const int OFF_H   = 4*Bn*Tn*Ln;
  const int OFF_Z   = 4*Bn*Tn*Ln + Bn*Tn*Hn;

  float freg = 0.f, areg = 0.f, epsr = 0.f;

  for (int t = 0; t < Tn; t++){
    const int bt = b*Tn + t;

    if (t > 0 && tid >= 64 && tid < 320) sh_hfh[128 + tid - 64] = (_Float16)freg;
    if (t < Tn-1){
      if (tid >= 64 && tid < 320) freg = feats[(size_t)(bt+1)*FDn + (tid-64)];
      if (tid >= 320 && tid < 326) areg = actions[(size_t)(bt+1)*An + (tid-320)];
    }
    if (tid >= 128 && ((tid-128)&7) == 0) epsr = eps[(size_t)bt*Ln + ((tid-128)>>3)];

    {
      float a0 = bih_i, a1 = 0.f;
#pragma unroll
      for (int c = 0; c < 19; c += 2) a0 = fdot2u(wih[c], X2[c], a0);
#pragma unroll
      for (int c = 1; c < 19; c += 2) a1 = fdot2u(wih[c], X2[c], a1);
      sh_gi[tid] = a0 + a1;

      float g0 = bhh_i, g1 = 0.f, g2 = 0.f, g3 = 0.f;
#pragma unroll
      for (int k8 = 0; k8 < 16; k8++){
        uint4 w = whhr[k8];
        uint4 h = H4[k8];
        g0 = fdot2u(w.x, h.x, g0);
        g1 = fdot2u(w.y, h.y, g1);
        g2 = fdot2u(w.z, h.z, g2);
        g3 = fdot2u(w.w, h.w, g3);
      }
      sh_gh[tid] = (g0 + g1) + (g2 + g3);
    }
    BAR_LDS();

    if (tid < Hn){
      const float r  = sigmoid_fast(sh_gi[tid]       + sh_gh[tid]);
      const float zg = sigmoid_fast(sh_gi[Hn  + tid] + sh_gh[Hn  + tid]);
      const float nn = tanh_fast(fmaf(r, sh_gh[2*Hn + tid], sh_gi[2*Hn + tid]));
      hreg = (1.f - zg)*nn + zg*hreg;
      sh_hfh[tid] = (_Float16)hreg;
      out[OFF_H + (size_t)bt*Hn + tid] = hreg;
    }
    if (t < Tn-1 && tid >= 320 && tid < 326) sh_xh[32 + tid - 320] = (_Float16)areg;
    BAR_LDS();

    if (tid < 128){
      const int j = tid & 1;
      float a0 = 0.f, a1 = 0.f, a2 = 0.f, a3 = 0.f;
#pragma unroll
      for (int c4 = 0; c4 < 8; c4++){
        uint4 h = H4[8*j + c4];
        a0 = fdot2u(prw[4*c4+0], h.x, a0);
        a1 = fdot2u(prw[4*c4+1], h.y, a1);
        a2 = fdot2u(prw[4*c4+2], h.z, a2);
        a3 = fdot2u(prw[4*c4+3], h.w, a3);
      }
      float p = (a0 + a1) + (a2 + a3);
      p += __shfl_xor(p, 1);
      if (j == 0){
        const int o = tid >> 1;
        p += prb;
        if (o < Ln) out[OFF_MUP + (size_t)bt*Ln + o] = p;
        else        out[OFF_LVP + (size_t)bt*Ln + (o - Ln)] = p;
      }
    } else {
      float a0 = 0.f, a1 = 0.f, a2 = 0.f, a3 = 0.f;
#pragma unroll
      for (int kk = 0; kk < 12; kk++){
        uint4 w = pww[kk];
        uint4 h = H4[pj*12 + kk];
        a0 = fdot2u(w.x, h.x, a0);
        a1 = fdot2u(w.y, h.y, a1);
        a2 = fdot2u(w.z, h.z, a2);
        a3 = fdot2u(w.w, h.w, a3);
      }
      float p = (a0 + a1) + (a2 + a3);
      p += __shfl_xor(p, 1);
      p += __shfl_xor(p, 2);
      p += pob;
      const float q_part = __shfl_xor(p, 4);
      if (pj == 0){
        if (is_mu){
          const int o = om >> 1;
          out[OFF_MUQ + (size_t)bt*Ln + o] = p;
          const float zz = fmaf(__expf(0.5f*q_part), epsr, p);
          sh_xh[o] = (_Float16)zz;
          out[OFF_Z + (size_t)bt*Ln + o] = zz;
        } else {
          out[OFF_LVQ + (size_t)bt*Ln + (o_p - Ln)] = p;
        }
      }
    }
    BAR_LDS();
  }
}

// ---------------------------------------------------------------------------
extern "C" void kernel_launch(void* const* d_in, const int* in_sizes, int n_in,
                              void* d_out, int out_size, void* d_ws, size_t ws_size,
                              hipStream_t stream)
{
  const float* states = (const float*)d_in[0];
  const float* actions= (const float*)d_in[1];
  const float* c1_w = (const float*)d_in[2];  const float* c1_b = (const float*)d_in[3];
  const float* c2_w = (const float*)d_in[4];  const float* c2_b = (const float*)d_in[5];
  const float* c3_w = (const float*)d_in[6];  const float* c3_b = (const float*)d_in[7];
  const float* c4_w = (const float*)d_in[8];  const float* c4_b = (const float*)d_in[9];
  const float* fc_w = (const float*)d_in[10]; const float* fc_b = (const float*)d_in[11];
  const float* gwih = (const float*)d_in[12]; const float* gwhh = (const float*)d_in[13];
  const float* gbih = (const float*)d_in[14]; const float* gbhh = (const float*)d_in[15];
  const float* pr_w = (const float*)d_in[16]; const float* pr_b = (const float*)d_in[17];
  const float* po_w = (const float*)d_in[18]; const float* po_b = (const float*)d_in[19];
  const float* eps  = (const float*)d_in[20];

  char* p = (char*)d_ws;
  auto alloc = [&](size_t bytes){ char* r = p; p += (bytes + 255) & ~255ULL; return r; };

  unsigned short* statesB = (unsigned short*)alloc((size_t)Nimg*4096*4*2); // NHWC c=4
  unsigned short* act1    = (unsigned short*)alloc((size_t)Nimg*1024*32*2);
  unsigned short* act2    = (unsigned short*)alloc((size_t)Nimg*256*64*2);
  unsigned short* act3    = (unsigned short*)alloc((size_t)Nimg*64*128*2);
  unsigned short* act4    = (unsigned short*)alloc((size_t)Nimg*16*256*2);
  float*          feats   = (float*)alloc((size_t)Nimg*FDn*4);
  unsigned short* w1p     = (unsigned short*)alloc(32*64*2);
  unsigned short* w2p     = (unsigned short*)alloc((size_t)64*512*2);
  unsigned short* w3p     = (unsigned short*)alloc((size_t)128*1024*2);
  unsigned short* w4p     = (unsigned short*)alloc((size_t)256*2048*2);
  unsigned short* wfcp    = (unsigned short*)alloc((size_t)256*4096*2);
  unsigned* g_scan = (unsigned*)alloc((size_t)SCAN_U*4);
  unsigned* g_wih2 = (unsigned*)alloc((size_t)19*384*4);
  unsigned* g_pr2  = (unsigned*)alloc((size_t)64*64*4);

  states_nhwc_kernel<<<Nimg*4096/256, 256, 0, stream>>>(states, statesB);
  prep2_kernel<<<6981, 256, 0, stream>>>(c1_w, c2_w, c3_w, c4_w, fc_w,
                                         gwhh, gwih, pr_w, po_w,
                                         w1p, w2p, w3p, w4p, wfcp,
                                         g_scan, g_wih2, g_pr2);

  // encoder: NHWC implicit-GEMM MFMA convs (BM=128, swizzled dbuf)
  convN_mfma<4,64,32,32,32,10>  <<< dim3(Nimg*1024/128, 1), 256, 0, stream >>>(statesB, w1p, c1_b, act1);
  convN_mfma<32,32,64,16,64,8>  <<< dim3(Nimg*256/128, 1), 256, 0, stream >>>(act1, w2p, c2_b, act2);
  convN_mfma<64,16,128,8,64,6>  <<< dim3(Nimg*64/128, 2), 256, 0, stream >>>(act2, w3p, c3_b, act3);
  convN_mfma<128,8,256,4,64,4>  <<< dim3(Nimg*16/128, 4), 256, 0, stream >>>(act3, w4p, c4_b, act4);

  fc_mfma2<<< dim3(Nimg/64, 4), 256, 0, stream >>>(act4, wfcp, fc_b, feats);

  rssm_scan4<<< Bn, 384, 0, stream >>>(actions, feats, eps,
                                       g_scan, g_wih2, g_pr2,
                                       gbih, gbhh, pr_b, po_b, (float*)d_out);
}